// Round 10
// baseline (347.142 us; speedup 1.0000x reference)
//
#include <hip/hip_runtime.h>

typedef __bf16 bf16;
typedef bf16 bf16x4 __attribute__((ext_vector_type(4)));
typedef bf16 bf16x8 __attribute__((ext_vector_type(8)));
typedef float f32x4 __attribute__((ext_vector_type(4)));

#define B_ 2
#define S_ 4096
#define D_ 1024
#define QSTR 3328   // fused qkv+rq row stride

__device__ __forceinline__ void gload_lds16(const void* g, void* l) {
  __builtin_amdgcn_global_load_lds((const __attribute__((address_space(1))) void*)g,
                                   (__attribute__((address_space(3))) void*)l, 16, 0, 0);
}

// ---------------- fused prep: 4 weight transposes + convert + pool/rkv GEMV + bias ----
__device__ __forceinline__ void transpose_block(
    const float* __restrict__ in, bf16* __restrict__ out, int K, int N,
    int bx, int by, float (*tile)[33], int tx, int ty)
{
  const int nb = bx * 32, kb = by * 32;
#pragma unroll
  for (int j = 0; j < 4; j++)
    tile[ty + j * 8][tx] = in[(size_t)(kb + ty + j * 8) * N + nb + tx];
  __syncthreads();
#pragma unroll
  for (int j = 0; j < 4; j++)
    out[(size_t)(nb + ty + j * 8) * K + kb + tx] = (bf16)tile[tx][ty + j * 8];
}

__global__ __launch_bounds__(256) void prep_kernel(
    const float* __restrict__ qkv_w, const float* __restrict__ rq_w,
    const float* __restrict__ rkv_w, const float* __restrict__ rout_w,
    const float* __restrict__ out_w, const float* __restrict__ x,
    const float* __restrict__ qkv_b, const float* __restrict__ rq_b,
    const float* __restrict__ rkv_b,
    bf16* __restrict__ qkvr_wt, bf16* __restrict__ rout_wt,
    bf16* __restrict__ out_wt, bf16* __restrict__ xb,
    float* __restrict__ qkvr_b, bf16* __restrict__ rkvb)
{
  __shared__ float smem[1056];
  float (*tile)[33] = (float(*)[33])smem;
  const int t = threadIdx.x;
  const int tx = t & 31, ty = t >> 5;
  int bid = blockIdx.x;
  if (bid < 3072) {        // qkv_w [1024][3072] -> qkvr_wt[0:3072][1024]
    transpose_block(qkv_w, qkvr_wt, 1024, 3072, bid % 96, bid / 96, tile, tx, ty);
    return;
  }
  bid -= 3072;
  if (bid < 256) {         // rq_w [1024][256] -> qkvr_wt[3072:3328][1024]
    transpose_block(rq_w, qkvr_wt + (size_t)3072 * 1024, 1024, 256, bid % 8, bid / 8, tile, tx, ty);
    return;
  }
  bid -= 256;
  if (bid < 256) {         // rout_w [256][1024] -> rout_wt[1024][256]
    transpose_block(rout_w, rout_wt, 256, 1024, bid % 32, bid / 32, tile, tx, ty);
    return;
  }
  bid -= 256;
  if (bid < 1024) {        // out_w [1024][1024] -> out_wt[1024][1024]
    transpose_block(out_w, out_wt, 1024, 1024, bid % 32, bid / 32, tile, tx, ty);
    return;
  }
  bid -= 1024;
  if (bid < 2048) {        // convert x -> xb
    const int n4 = B_ * S_ * 1024 / 4;
    for (int i = bid * 256 + t; i < n4; i += 2048 * 256) {
      const float4 v = ((const float4*)x)[i];
      bf16x4 o = {(bf16)v.x, (bf16)v.y, (bf16)v.z, (bf16)v.w};
      *(bf16x4*)&xb[i * 4] = o;
    }
    return;
  }
  bid -= 2048;
  if (bid < 128) {         // pool (from f32 x) + rkv GEMV (from f32 rkv_w)
    float* prow = smem;    // [1024]
    const int b = bid >> 6, lt = bid & 63;
    const float* px = x + ((size_t)b * S_ + lt * 64) * 1024 + t * 4;
    float4 s4 = {0.f, 0.f, 0.f, 0.f};
#pragma unroll
    for (int c = 0; c < 64; c++) {
      const float4 v = *(const float4*)(px + (size_t)c * 1024);
      s4.x += v.x; s4.y += v.y; s4.z += v.z; s4.w += v.w;
    }
    prow[t * 4 + 0] = s4.x * 0.015625f;
    prow[t * 4 + 1] = s4.y * 0.015625f;
    prow[t * 4 + 2] = s4.z * 0.015625f;
    prow[t * 4 + 3] = s4.w * 0.015625f;
    __syncthreads();
    float s0 = rkv_b[2 * t], s1 = rkv_b[2 * t + 1];
#pragma unroll 4
    for (int k = 0; k < 1024; k++) {
      const float2 wv = *(const float2*)&rkv_w[(size_t)k * 512 + 2 * t];
      const float p = prow[k];
      s0 += p * wv.x; s1 += p * wv.y;
    }
    rkvb[(size_t)bid * 512 + 2 * t] = (bf16)s0;
    rkvb[(size_t)bid * 512 + 2 * t + 1] = (bf16)s1;
    return;
  }
  bid -= 128;
  {                        // fused bias vector
    for (int i = t; i < 3072; i += 256) qkvr_b[i] = qkv_b[i];
    if (t < 256) qkvr_b[3072 + t] = rq_b[t];
  }
}

// ---------------- 128-tile GEMM (balanced grids for N<=1024 shapes) ----------------
template <typename OutT>
__global__ __launch_bounds__(256) void gemm_bias_kernel(
    const bf16* __restrict__ A, const bf16* __restrict__ Bt,
    const float* __restrict__ bias, OutT* __restrict__ C,
    int M, int N, int K)
{
  __shared__ __align__(16) bf16 Al[128 * 32];
  __shared__ __align__(16) bf16 Bl[128 * 32];
  const int m0 = blockIdx.x * 128;
  const int n0 = blockIdx.y * 128;
  const int t = threadIdx.x;
  const int lane = t & 63;
  const int wave = t >> 6;
  const int wr = (wave >> 1) * 64;
  const int wc = (wave & 1) * 64;
  const int r16 = lane & 15;
  const int kg = lane >> 4;

  f32x4 acc[4][4];
#pragma unroll
  for (int i = 0; i < 4; i++)
#pragma unroll
    for (int j = 0; j < 4; j++) {
      f32x4 z = {0.f, 0.f, 0.f, 0.f};
      acc[i][j] = z;
    }

  for (int k0 = 0; k0 < K; k0 += 32) {
    __syncthreads();
#pragma unroll
    for (int i = 0; i < 2; i++) {
      const int o = i * 4096 + wave * 1024 + lane * 16;
      const int r = o >> 6;
      const int cb = o & 63;
      gload_lds16((const char*)(A + (size_t)(m0 + r) * K + k0) + cb,
                  (char*)Al + i * 4096 + wave * 1024);
      gload_lds16((const char*)(Bt + (size_t)(n0 + r) * K + k0) + cb,
                  (char*)Bl + i * 4096 + wave * 1024);
    }
    __syncthreads();
    bf16x8 a[4], b[4];
#pragma unroll
    for (int i = 0; i < 4; i++)
      a[i] = *(const bf16x8*)&Al[(wr + i * 16 + r16) * 32 + kg * 8];
#pragma unroll
    for (int i = 0; i < 4; i++)
      b[i] = *(const bf16x8*)&Bl[(wc + i * 16 + r16) * 32 + kg * 8];
#pragma unroll
    for (int i = 0; i < 4; i++)
#pragma unroll
      for (int j = 0; j < 4; j++)
        acc[i][j] = __builtin_amdgcn_mfma_f32_16x16x32_bf16(a[i], b[j], acc[i][j], 0, 0, 0);
  }

  float bs[4];
#pragma unroll
  for (int j = 0; j < 4; j++) bs[j] = bias[n0 + wc + j * 16 + r16];
#pragma unroll
  for (int i = 0; i < 4; i++)
#pragma unroll
    for (int j = 0; j < 4; j++)
#pragma unroll
      for (int r = 0; r < 4; r++) {
        const int row = m0 + wr + i * 16 + kg * 4 + r;
        const int col = n0 + wc + j * 16 + r16;
        C[(size_t)row * N + col] = (OutT)(acc[i][j][r] + bs[j]);
      }
}

// ---------------- 256x256 8-phase GEMM (frozen) ----------------
template <typename OutT>
__global__ __launch_bounds__(512, 1) void gemm8_kernel(
    const bf16* __restrict__ A, const bf16* __restrict__ Bt,
    const float* __restrict__ bias, OutT* __restrict__ C,
    int M, int N, int K)
{
  __shared__ __align__(16) bf16 Al[2][256 * 64];
  __shared__ __align__(16) bf16 Bl[2][256 * 64];

  const int nbx = gridDim.x;
  const int nwg = nbx * gridDim.y;
  int bid = blockIdx.y * nbx + blockIdx.x;
  bid = (bid & 7) * (nwg >> 3) + (bid >> 3);   // XCD swizzle (nwg % 8 == 0)
  const int m0 = (bid % nbx) * 256;
  const int n0 = (bid / nbx) * 256;

  const int t = threadIdx.x;
  const int lane = t & 63;
  const int w = t >> 6;
  const int wm = w >> 2;
  const int wn = w & 3;
  const int l15 = lane & 15;
  const int kg = lane >> 4;

  const int srow = t >> 3;
  const int schunk = (t & 7) ^ (srow & 7);
  const bf16* Aaddr = A + (size_t)(m0 + srow) * K + schunk * 8;
  const bf16* Baddr = Bt + (size_t)(n0 + srow) * K + schunk * 8;

  const int NT = K >> 6;
  const int NITER = NT >> 1;

  const int arow = wm * 128 + l15;
  const int brow = wn * 64 + l15;
  const int c0 = (kg ^ (l15 & 7)) * 16;
  const int c1 = ((4 + kg) ^ (l15 & 7)) * 16;

  f32x4 acc[8][4];
#pragma unroll
  for (int i = 0; i < 8; i++)
#pragma unroll
    for (int j = 0; j < 4; j++) { f32x4 z = {0, 0, 0, 0}; acc[i][j] = z; }

#define STG_A(buf, q, kt) gload_lds16(Aaddr + (size_t)(q) * 64 * K + (kt) * 64, \
                                      (char*)&Al[buf][0] + (q) * 8192 + w * 1024)
#define STG_B(buf, q, kt) gload_lds16(Baddr + (size_t)(q) * 64 * K + (kt) * 64, \
                                      (char*)&Bl[buf][0] + (q) * 8192 + w * 1024)
#define RD_A(buf, aq) \
  _Pragma("unroll") for (int ii = 0; ii < 4; ii++) { \
    const char* p_ = (const char*)&Al[buf][0] + (size_t)(arow + (aq) * 64 + ii * 16) * 128; \
    af[ii][0] = *(const bf16x8*)(p_ + c0); \
    af[ii][1] = *(const bf16x8*)(p_ + c1); }
#define RD_B(buf) \
  _Pragma("unroll") for (int jj = 0; jj < 4; jj++) { \
    const char* p_ = (const char*)&Bl[buf][0] + (size_t)(brow + jj * 16) * 128; \
    bfr[jj][0] = *(const bf16x8*)(p_ + c0); \
    bfr[jj][1] = *(const bf16x8*)(p_ + c1); }
#define MM(iofs, j0) \
  _Pragma("unroll") for (int ii = 0; ii < 4; ii++) \
  _Pragma("unroll") for (int jj = (j0); jj < (j0) + 2; jj++) { \
    acc[(iofs) + ii][jj] = __builtin_amdgcn_mfma_f32_16x16x32_bf16(af[ii][0], bfr[jj][0], acc[(iofs) + ii][jj], 0, 0, 0); \
    acc[(iofs) + ii][jj] = __builtin_amdgcn_mfma_f32_16x16x32_bf16(af[ii][1], bfr[jj][1], acc[(iofs) + ii][jj], 0, 0, 0); }
#define BARX __builtin_amdgcn_s_barrier()
#define LGKM0 do { asm volatile("s_waitcnt lgkmcnt(0)" ::: "memory"); \
                   __builtin_amdgcn_sched_barrier(0); } while (0)
#define PRI1 __builtin_amdgcn_s_setprio(1)
#define PRI0 __builtin_amdgcn_s_setprio(0)

#pragma unroll
  for (int q = 0; q < 4; q++) { STG_B(0, q, 0); }
#pragma unroll
  for (int q = 0; q < 4; q++) { STG_A(0, q, 0); }
#pragma unroll
  for (int q = 0; q < 4; q++) { STG_B(1, q, 1); }
#pragma unroll
  for (int q = 0; q < 4; q++) { STG_A(1, q, 1); }
  asm volatile("s_waitcnt vmcnt(8)" ::: "memory");
  BARX;

  bf16x8 af[4][2], bfr[4][2];

  for (int it = 0; it < NITER; it++) {
    const int kt0 = 2 * it;
    const bool st = (it + 1) < NITER;

    RD_A(0, 0); RD_B(0);
    BARX; LGKM0; PRI1; MM(0, 0); PRI0; BARX;
    if (st) { STG_B(0, 0, kt0 + 2); STG_B(0, 1, kt0 + 2); }
    PRI1; MM(0, 2); PRI0; BARX;
    RD_A(0, 1);
    if (st) { STG_B(0, 2, kt0 + 2); STG_B(0, 3, kt0 + 2); }
    BARX; LGKM0; PRI1; MM(4, 0); PRI0; BARX;
    if (st) { STG_A(0, 0, kt0 + 2); STG_A(0, 2, kt0 + 2); }
    PRI1; MM(4, 2); PRI0;
    asm volatile("s_waitcnt vmcnt(6)" ::: "memory");
    BARX;

    RD_A(1, 0); RD_B(1);
    if (st) { STG_A(0, 1, kt0 + 2); STG_A(0, 3, kt0 + 2); }
    BARX; LGKM0; PRI1; MM(0, 0); PRI0; BARX;
    if (st) { STG_B(1, 0, kt0 + 3); STG_B(1, 1, kt0 + 3); }
    PRI1; MM(0, 2); PRI0; BARX;
    RD_A(1, 1);
    if (st) { STG_B(1, 2, kt0 + 3); STG_B(1, 3, kt0 + 3); }
    BARX; LGKM0; PRI1; MM(4, 0); PRI0; BARX;
    if (st) { STG_A(1, 0, kt0 + 3); STG_A(1, 1, kt0 + 3);
              STG_A(1, 2, kt0 + 3); STG_A(1, 3, kt0 + 3); }
    PRI1; MM(4, 2); PRI0;
    asm volatile("s_waitcnt vmcnt(8)" ::: "memory");
    BARX;
  }

#undef STG_A
#undef STG_B
#undef RD_A
#undef RD_B
#undef MM
#undef BARX
#undef LGKM0
#undef PRI1
#undef PRI0

  float bs[4];
#pragma unroll
  for (int j = 0; j < 4; j++) bs[j] = bias[n0 + wn * 64 + j * 16 + l15];
#pragma unroll
  for (int i = 0; i < 8; i++)
#pragma unroll
    for (int j = 0; j < 4; j++)
#pragma unroll
      for (int rr = 0; rr < 4; rr++) {
        const int row = m0 + wm * 128 + i * 16 + kg * 4 + rr;
        const int col = n0 + wn * 64 + j * 16 + l15;
        C[(size_t)row * N + col] = (OutT)(acc[i][j][rr] + bs[j]);
      }
}

// ---------------- latent attention (rq read from fused qkvrb) ----------------
__global__ __launch_bounds__(256) void latent_attn_kernel(
    const bf16* __restrict__ qkvrb, const bf16* __restrict__ rkvb,
    bf16* __restrict__ latout)
{
  __shared__ float rq_s[256];
  __shared__ float attn_s[4][64];
  const int blk = blockIdx.x;
  const int b = blk >> 12, s = blk & 4095;
  const int t = threadIdx.x;
  const int h = t >> 6, l = t & 63;
  const int cid = s >> 6;
  rq_s[t] = (float)qkvrb[((size_t)b * S_ + s) * QSTR + 3072 + t];
  __syncthreads();
  float val = -1e30f;
  if (l < cid) {
    const bf16* kr = rkvb + (size_t)(b * 64 + l) * 512 + h * 64;
    float sum = 0.f;
#pragma unroll
    for (int c = 0; c < 8; c++) {
      bf16x8 kv = *(const bf16x8*)(kr + c * 8);
#pragma unroll
      for (int j = 0; j < 8; j++) sum += rq_s[h * 64 + c * 8 + j] * (float)kv[j];
    }
    val = sum * 0.125f;
  }
  float mx = val;
#pragma unroll
  for (int off = 32; off; off >>= 1) mx = fmaxf(mx, __shfl_xor(mx, off));
  const float p = (l < cid) ? __expf(val - mx) : 0.f;
  float sm = p;
#pragma unroll
  for (int off = 32; off; off >>= 1) sm += __shfl_xor(sm, off);
  attn_s[h][l] = (sm > 0.f) ? p / sm : 0.f;
  __syncthreads();
  float o = 0.f;
  const bf16* vb = rkvb + (size_t)b * 64 * 512 + 256 + h * 64 + l;
  for (int lat = 0; lat < cid; lat++) o += attn_s[h][lat] * (float)vb[(size_t)lat * 512];
  latout[((size_t)b * S_ + s) * 256 + h * 64 + l] = (bf16)o;
}

// ---------------- local windowed attention + gate + mix (fused epilogue) ----------------
__global__ __launch_bounds__(256) void local_attn_gate(
    const bf16* __restrict__ qkv, const bf16* __restrict__ remote,
    const float* __restrict__ glw, const float* __restrict__ grw,
    bf16* __restrict__ mixedb)
{
  __shared__ __align__(16) bf16 Kl[128 * 72];
  __shared__ __align__(16) bf16 Vt[64 * 136];

  const int q0 = blockIdx.x * 128;
  const int h  = blockIdx.y;
  const int b  = blockIdx.z;
  const int t  = threadIdx.x;
  const int w  = t >> 6;
  const int l  = t & 63;
  const int g  = l >> 4;
  const int l15 = l & 15;

  const bf16* qbase = qkv + (size_t)b * S_ * QSTR + h * 64;
  const bf16* kbase = qbase + 1024;
  const bf16* vbase = qbase + 2048;

  bf16* PlW = &Kl[w * 32 * 72];

  const int kq = (t & 31) * 4;
  const int dh = (t >> 5) * 8;

  bf16x8 qf[2][2];
#pragma unroll
  for (int qg = 0; qg < 2; qg++)
#pragma unroll
    for (int db = 0; db < 2; db++)
      qf[qg][db] = *(const bf16x8*)(qbase + (size_t)(q0 + w * 32 + qg * 16 + l15) * QSTR + db * 32 + g * 8);

  float m_[2][4], l_[2][4];
  f32x4 accO[2][4];
#pragma unroll
  for (int qg = 0; qg < 2; qg++) {
#pragma unroll
    for (int r = 0; r < 4; r++) { m_[qg][r] = -1e30f; l_[qg][r] = 0.f; }
#pragma unroll
    for (int dt = 0; dt < 4; dt++) { f32x4 z = {0,0,0,0}; accO[qg][dt] = z; }
  }

  const int tstart = (q0 == 0) ? 1 : 0;

  bf16x8 kreg[4], vreg[4];
  {
    const int base = q0 - 128 + tstart * 128;
#pragma unroll
    for (int i = 0; i < 4; i++) {
      const int c = i * 256 + t;
      const int kk = c >> 3, dc = c & 7;
      kreg[i] = *(const bf16x8*)(kbase + (size_t)(base + kk) * QSTR + dc * 8);
    }
#pragma unroll
    for (int i = 0; i < 4; i++)
      vreg[i] = *(const bf16x8*)(vbase + (size_t)(base + kq + i) * QSTR + dh);
  }

  for (int tile = tstart; tile < 2; tile++) {
    __syncthreads();
#pragma unroll
    for (int i = 0; i < 4; i++) {
      const int c = i * 256 + t;
      const int kk = c >> 3, dc = c & 7;
      *(bf16x8*)&Kl[kk * 72 + dc * 8] = kreg[i];
    }
#pragma unroll
    for (int j = 0; j < 8; j++) {
      bf16x4 wv = {vreg[0][j], vreg[1][j], vreg[2][j], vreg[3][j]};
      *(bf16x4*)&Vt[(dh + j) * 136 + kq] = wv;
    }
    __syncthreads();
    if (tile == 0) {
#pragma unroll
      for (int i = 0; i < 4; i++) {
        const int c = i * 256 + t;
        const int kk = c >> 3, dc = c & 7;
        kreg[i] = *(const bf16x8*)(kbase + (size_t)(q0 + kk) * QSTR + dc * 8);
      }
#pragma unroll
      for (int i = 0; i < 4; i++)
        vreg[i] = *(const bf16x8*)(vbase + (size_t)(q0 + kq + i) * QSTR + dh);
    }

    const int kt_lo = (tile == 0) ? 2 * w : 0;
    const int kt_hi = (tile == 0) ? 8 : 2 * w + 2;
    const int nkt = kt_hi - kt_lo;

    f32x4 s[2][8];
#pragma unroll
    for (int qg = 0; qg < 2; qg++)
#pragma unroll
      for (int kk = 0; kk < 8; kk++) { f32x4 z = {0,0,0,0}; s[qg][kk] = z; }

#pragma unroll
    for (int kk = 0; kk < 8; kk++) {
      if (kk >= nkt) continue;
      const int kt = kt_lo + kk;
      const bf16x8 kf0 = *(const bf16x8*)&Kl[(kt * 16 + l15) * 72 + g * 8];
      const bf16x8 kf1 = *(const bf16x8*)&Kl[(kt * 16 + l15) * 72 + 32 + g * 8];
      s[0][kk] = __builtin_amdgcn_mfma_f32_16x16x32_bf16(qf[0][0], kf0, s[0][kk], 0, 0, 0);
      s[0][kk] = __builtin_amdgcn_mfma_f32_16x16x32_bf16(qf[0][1], kf1, s[0][kk], 0, 0, 0);
      s[1][kk] = __builtin_amdgcn_mfma_f32_16x16x32_bf16(qf[1][0], kf0, s[1][kk], 0, 0, 0);
      s[1][kk] = __builtin_amdgcn_mfma_f32_16x16x32_bf16(qf[1][1], kf1, s[1][kk], 0, 0, 0);
    }
    asm volatile("s_waitcnt lgkmcnt(0)" ::: "memory");
    __builtin_amdgcn_s_barrier();

#pragma unroll
    for (int qg = 0; qg < 2; qg++) {
#pragma unroll
      for (int kk = 0; kk < 8; kk++) {
        if (kk >= nkt) continue;
        const int kr = (kt_lo + kk) * 16 + l15;
#pragma unroll
        for (int r = 0; r < 4; r++) {
          const int qr = w * 32 + qg * 16 + g * 4 + r;
          const bool ok = (tile == 0) ? (kr >= qr) : (kr < qr);
          s[qg][kk][r] = ok ? s[qg][kk][r] * 0.125f : -1e9f;
        }
      }
      float corr[4];
#pragma unroll
      for (int r = 0; r < 4; r++) {
        float v = -1e30f;
#pragma unroll
        for (int kk = 0; kk < 8; kk++) { if (kk >= nkt) continue; v = fmaxf(v, s[qg][kk][r]); }
        v = fmaxf(v, __shfl_xor(v, 1));
        v = fmaxf(v, __shfl_xor(v, 2));
        v = fmaxf(v, __shfl_xor(v, 4));
        v = fmaxf(v, __shfl_xor(v, 8));
        const float mn = fmaxf(m_[qg][r], v);
        corr[r] = __expf(m_[qg][r] - mn);
        m_[qg][r] = mn;
      }
      float rs[4] = {0.f, 0.f, 0.f, 0.f};
#pragma unroll
      for (int kk = 0; kk < 8; kk++) {
        if (kk >= nkt) continue;
        const int kt = kt_lo + kk;
#pragma unroll
        for (int r = 0; r < 4; r++) {
          const float sv = s[qg][kk][r];
          const float p = (sv > -5e8f) ? __expf(sv - m_[qg][r]) : 0.f;
          rs[r] += p;
          PlW[(g * 4 + r) * 136 + kt * 16 + l15] = (bf16)p;
        }
      }
#pragma unroll
      for (int r = 0; r < 4; r++) {
        float v = rs[r];
        v += __shfl_xor(v, 1); v += __shfl_xor(v, 2);
        v += __shfl_xor(v, 4); v += __shfl_xor(v, 8);
        l_[qg][r] = l_[qg][r] * corr[r] + v;
#pragma unroll
        for (int dt = 0; dt < 4; dt++) accO[qg][dt][r] *= corr[r];
      }
      asm volatile("s_waitcnt lgkmcnt(0)" ::: "memory");
      __builtin_amdgcn_sched_barrier(0);
      const int kc_lo = (tile == 0) ? w : 0;
      const int kc_hi = (tile == 0) ? 4 : w + 1;
#pragma unroll
      for (int kc = 0; kc < 4; kc++) {
        if (kc < kc_lo || kc >= kc_hi) continue;
        const bf16x8 pa = *(const bf16x8*)&PlW[l15 * 136 + kc * 32 + g * 8];
#pragma unroll
        for (int dt = 0; dt < 4; dt++) {
          const bf16x8 vf = *(const bf16x8*)&Vt[(dt * 16 + l15) * 136 + kc * 32 + g * 8];
          accO[qg][dt] = __builtin_amdgcn_mfma_f32_16x16x32_bf16(pa, vf, accO[qg][dt], 0, 0, 0);
        }
      }
    }
  }

  // ---- fused gate + mix epilogue ----
  float glv[4], grv[4];
#pragma unroll
  for (int dt = 0; dt < 4; dt++) {
    glv[dt] = glw[dt * 16 + l15];
    grv[dt] = grw[dt * 16 + l15];
  }
  bf16* outp = mixedb + ((size_t)b * S_ + q0 + w * 32) * 1024 + h * 64;
  const bf16* rbase = remote + ((size_t)b * S_ + q0 + w * 32) * 1024 + h * 64;
#pragma unroll
  for (int qg = 0; qg < 2; qg++)
#pragma unroll
    for (int r = 0; r < 4; r++) {
      const int row = qg * 16 + g * 4 + r;
      const float inv = (l_[qg][r] > 0.f) ? 1.f / l_[qg][r] : 0.f;
      float lv[4], rv[4];
      float part = 0.f;
#pragma unroll
      for (int dt = 0; dt < 4; dt++) {
        lv[dt] = accO[qg][dt][r] * inv;
        rv[dt] = (float)rbase[(size_t)row * 1024 + dt * 16 + l15];
        part += lv[dt] * glv[dt] + rv[dt] * grv[dt];
      }
      part += __shfl_xor(part, 1);
      part += __shfl_xor(part, 2);
      part += __shfl_xor(part, 4);
      part += __shfl_xor(part, 8);
      const float gg = 1.f / (1.f + __expf(-part));
#pragma unroll
      for (int dt = 0; dt < 4; dt++)
        outp[(size_t)row * 1024 + dt * 16 + l15] = (bf16)(gg * lv[dt] + (1.f - gg) * rv[dt]);
    }
}

// ---------------- launch ----------------
extern "C" void kernel_launch(void* const* d_in, const int* in_sizes, int n_in,
                              void* d_out, int out_size, void* d_ws, size_t ws_size,
                              hipStream_t stream)
{
  const float* x      = (const float*)d_in[0];
  const float* qkv_w  = (const float*)d_in[1];
  const float* qkv_b  = (const float*)d_in[2];
  const float* rq_w   = (const float*)d_in[3];
  const float* rq_b   = (const float*)d_in[4];
  const float* rkv_w  = (const float*)d_in[5];
  const float* rkv_b  = (const float*)d_in[6];
  const float* rout_w = (const float*)d_in[7];
  const float* rout_b = (const float*)d_in[8];
  const float* out_w  = (const float*)d_in[9];
  const float* out_b  = (const float*)d_in[10];
  const float* gl_w   = (const float*)d_in[11];
  const float* gr_w   = (const float*)d_in[12];

  char* w = (char*)d_ws;
  bf16* qkvr_wt = (bf16*)w; w += (size_t)QSTR * 1024 * 2;
  bf16* rout_wt = (bf16*)w; w += (size_t)1024 * 256 * 2;
  bf16* out_wt  = (bf16*)w; w += (size_t)1024 * 1024 * 2;
  float* qkvr_b = (float*)w; w += (size_t)QSTR * 4;
  bf16* xb      = (bf16*)w; w += (size_t)B_ * S_ * 1024 * 2;
  bf16* qkvrb   = (bf16*)w; w += (size_t)B_ * S_ * QSTR * 2;
  bf16* rkvb    = (bf16*)w; w += (size_t)B_ * 64 * 512 * 2;
  bf16* latout  = (bf16*)w; w += (size_t)B_ * S_ * 256 * 2;
  bf16* remote  = (bf16*)w; w += (size_t)B_ * S_ * 1024 * 2;
  bf16* mixedb  = (bf16*)w; w += (size_t)B_ * S_ * 1024 * 2;

  prep_kernel<<<dim3(6785), 256, 0, stream>>>(qkv_w, rq_w, rkv_w, rout_w, out_w, x,
                                              qkv_b, rq_b, rkv_b,
                                              qkvr_wt, rout_wt, out_wt, xb, qkvr_b, rkvb);

  gemm8_kernel<bf16><<<dim3(32, 13), 512, 0, stream>>>(xb, qkvr_wt, qkvr_b, qkvrb, B_ * S_, QSTR, 1024);
  latent_attn_kernel<<<dim3(B_ * S_), 256, 0, stream>>>(qkvrb, rkvb, latout);
  gemm_bias_kernel<bf16><<<dim3(64, 8), 256, 0, stream>>>(latout, rout_wt, rout_b, remote, B_ * S_, 1024, 256);
  local_attn_gate<<<dim3(S_ / 128, 16, B_), 256, 0, stream>>>(qkvrb, remote, gl_w, gr_w, mixedb);
  gemm_bias_kernel<float><<<dim3(64, 8), 256, 0, stream>>>(mixedb, out_wt, out_b, (float*)d_out, B_ * S_, 1024, 1024);
}

// Round 11
// 252.334 us; speedup vs baseline: 1.3757x; 1.3757x over previous
//
#include <hip/hip_runtime.h>

typedef __bf16 bf16;
typedef bf16 bf16x4 __attribute__((ext_vector_type(4)));
typedef bf16 bf16x8 __attribute__((ext_vector_type(8)));
typedef float f32x4 __attribute__((ext_vector_type(4)));

#define B_ 2
#define S_ 4096
#define D_ 1024
#define QSTR 3328   // fused qkv+rq row stride

__device__ __forceinline__ void gload_lds16(const void* g, void* l) {
  __builtin_amdgcn_global_load_lds((const __attribute__((address_space(1))) void*)g,
                                   (__attribute__((address_space(3))) void*)l, 16, 0, 0);
}

// ---------------- fused prep: 5 weight transposes + convert + fused bias ----------------
__device__ __forceinline__ void transpose_block(
    const float* __restrict__ in, bf16* __restrict__ out, int K, int N,
    int bx, int by, float (*tile)[33], int tx, int ty)
{
  const int nb = bx * 32, kb = by * 32;
#pragma unroll
  for (int j = 0; j < 4; j++)
    tile[ty + j * 8][tx] = in[(size_t)(kb + ty + j * 8) * N + nb + tx];
  __syncthreads();
#pragma unroll
  for (int j = 0; j < 4; j++)
    out[(size_t)(nb + ty + j * 8) * K + kb + tx] = (bf16)tile[tx][ty + j * 8];
}

__global__ __launch_bounds__(256) void prep_kernel(
    const float* __restrict__ qkv_w, const float* __restrict__ rq_w,
    const float* __restrict__ rkv_w, const float* __restrict__ rout_w,
    const float* __restrict__ out_w, const float* __restrict__ x,
    const float* __restrict__ qkv_b, const float* __restrict__ rq_b,
    bf16* __restrict__ qkvr_wt, bf16* __restrict__ rkv_wt,
    bf16* __restrict__ rout_wt, bf16* __restrict__ out_wt,
    bf16* __restrict__ xb, float* __restrict__ qkvr_b)
{
  __shared__ float tile[32][33];
  const int t = threadIdx.x;
  const int tx = t & 31, ty = t >> 5;
  int bid = blockIdx.x;
  if (bid < 3072) {        // qkv_w [1024][3072] -> qkvr_wt[0:3072][1024]
    transpose_block(qkv_w, qkvr_wt, 1024, 3072, bid % 96, bid / 96, tile, tx, ty);
    return;
  }
  bid -= 3072;
  if (bid < 256) {         // rq_w [1024][256] -> qkvr_wt[3072:3328][1024]
    transpose_block(rq_w, qkvr_wt + (size_t)3072 * 1024, 1024, 256, bid % 8, bid / 8, tile, tx, ty);
    return;
  }
  bid -= 256;
  if (bid < 512) {         // rkv_w [1024][512] -> rkv_wt[512][1024]
    transpose_block(rkv_w, rkv_wt, 1024, 512, bid % 16, bid / 16, tile, tx, ty);
    return;
  }
  bid -= 512;
  if (bid < 256) {         // rout_w [256][1024] -> rout_wt[1024][256]
    transpose_block(rout_w, rout_wt, 256, 1024, bid % 32, bid / 32, tile, tx, ty);
    return;
  }
  bid -= 256;
  if (bid < 1024) {        // out_w [1024][1024] -> out_wt[1024][1024]
    transpose_block(out_w, out_wt, 1024, 1024, bid % 32, bid / 32, tile, tx, ty);
    return;
  }
  bid -= 1024;
  if (bid < 2048) {        // convert x -> xb
    const int n4 = B_ * S_ * 1024 / 4;
    for (int i = bid * 256 + t; i < n4; i += 2048 * 256) {
      const float4 v = ((const float4*)x)[i];
      bf16x4 o = {(bf16)v.x, (bf16)v.y, (bf16)v.z, (bf16)v.w};
      *(bf16x4*)&xb[i * 4] = o;
    }
    return;
  }
  {                        // fused bias vector
    for (int i = t; i < 3072; i += 256) qkvr_b[i] = qkv_b[i];
    if (t < 256) qkvr_b[3072 + t] = rq_b[t];
  }
}

// ---------------- 128-tile GEMM (balanced grids for N<=1024 shapes) ----------------
template <typename OutT>
__global__ __launch_bounds__(256) void gemm_bias_kernel(
    const bf16* __restrict__ A, const bf16* __restrict__ Bt,
    const float* __restrict__ bias, OutT* __restrict__ C,
    int M, int N, int K)
{
  __shared__ __align__(16) bf16 Al[128 * 32];
  __shared__ __align__(16) bf16 Bl[128 * 32];
  const int m0 = blockIdx.x * 128;
  const int n0 = blockIdx.y * 128;
  const int t = threadIdx.x;
  const int lane = t & 63;
  const int wave = t >> 6;
  const int wr = (wave >> 1) * 64;
  const int wc = (wave & 1) * 64;
  const int r16 = lane & 15;
  const int kg = lane >> 4;

  f32x4 acc[4][4];
#pragma unroll
  for (int i = 0; i < 4; i++)
#pragma unroll
    for (int j = 0; j < 4; j++) {
      f32x4 z = {0.f, 0.f, 0.f, 0.f};
      acc[i][j] = z;
    }

  for (int k0 = 0; k0 < K; k0 += 32) {
    __syncthreads();
#pragma unroll
    for (int i = 0; i < 2; i++) {
      const int o = i * 4096 + wave * 1024 + lane * 16;
      const int r = o >> 6;
      const int cb = o & 63;
      gload_lds16((const char*)(A + (size_t)(m0 + r) * K + k0) + cb,
                  (char*)Al + i * 4096 + wave * 1024);
      gload_lds16((const char*)(Bt + (size_t)(n0 + r) * K + k0) + cb,
                  (char*)Bl + i * 4096 + wave * 1024);
    }
    __syncthreads();
    bf16x8 a[4], b[4];
#pragma unroll
    for (int i = 0; i < 4; i++)
      a[i] = *(const bf16x8*)&Al[(wr + i * 16 + r16) * 32 + kg * 8];
#pragma unroll
    for (int i = 0; i < 4; i++)
      b[i] = *(const bf16x8*)&Bl[(wc + i * 16 + r16) * 32 + kg * 8];
#pragma unroll
    for (int i = 0; i < 4; i++)
#pragma unroll
      for (int j = 0; j < 4; j++)
        acc[i][j] = __builtin_amdgcn_mfma_f32_16x16x32_bf16(a[i], b[j], acc[i][j], 0, 0, 0);
  }

  float bs[4];
#pragma unroll
  for (int j = 0; j < 4; j++) bs[j] = bias[n0 + wc + j * 16 + r16];
#pragma unroll
  for (int i = 0; i < 4; i++)
#pragma unroll
    for (int j = 0; j < 4; j++)
#pragma unroll
      for (int r = 0; r < 4; r++) {
        const int row = m0 + wr + i * 16 + kg * 4 + r;
        const int col = n0 + wc + j * 16 + r16;
        C[(size_t)row * N + col] = (OutT)(acc[i][j][r] + bs[j]);
      }
}

// ---------------- 256x256 8-phase GEMM (frozen) ----------------
template <typename OutT>
__global__ __launch_bounds__(512, 1) void gemm8_kernel(
    const bf16* __restrict__ A, const bf16* __restrict__ Bt,
    const float* __restrict__ bias, OutT* __restrict__ C,
    int M, int N, int K)
{
  __shared__ __align__(16) bf16 Al[2][256 * 64];
  __shared__ __align__(16) bf16 Bl[2][256 * 64];

  const int nbx = gridDim.x;
  const int nwg = nbx * gridDim.y;
  int bid = blockIdx.y * nbx + blockIdx.x;
  bid = (bid & 7) * (nwg >> 3) + (bid >> 3);   // XCD swizzle (nwg % 8 == 0)
  const int m0 = (bid % nbx) * 256;
  const int n0 = (bid / nbx) * 256;

  const int t = threadIdx.x;
  const int lane = t & 63;
  const int w = t >> 6;
  const int wm = w >> 2;
  const int wn = w & 3;
  const int l15 = lane & 15;
  const int kg = lane >> 4;

  const int srow = t >> 3;
  const int schunk = (t & 7) ^ (srow & 7);
  const bf16* Aaddr = A + (size_t)(m0 + srow) * K + schunk * 8;
  const bf16* Baddr = Bt + (size_t)(n0 + srow) * K + schunk * 8;

  const int NT = K >> 6;
  const int NITER = NT >> 1;

  const int arow = wm * 128 + l15;
  const int brow = wn * 64 + l15;
  const int c0 = (kg ^ (l15 & 7)) * 16;
  const int c1 = ((4 + kg) ^ (l15 & 7)) * 16;

  f32x4 acc[8][4];
#pragma unroll
  for (int i = 0; i < 8; i++)
#pragma unroll
    for (int j = 0; j < 4; j++) { f32x4 z = {0, 0, 0, 0}; acc[i][j] = z; }

#define STG_A(buf, q, kt) gload_lds16(Aaddr + (size_t)(q) * 64 * K + (kt) * 64, \
                                      (char*)&Al[buf][0] + (q) * 8192 + w * 1024)
#define STG_B(buf, q, kt) gload_lds16(Baddr + (size_t)(q) * 64 * K + (kt) * 64, \
                                      (char*)&Bl[buf][0] + (q) * 8192 + w * 1024)
#define RD_A(buf, aq) \
  _Pragma("unroll") for (int ii = 0; ii < 4; ii++) { \
    const char* p_ = (const char*)&Al[buf][0] + (size_t)(arow + (aq) * 64 + ii * 16) * 128; \
    af[ii][0] = *(const bf16x8*)(p_ + c0); \
    af[ii][1] = *(const bf16x8*)(p_ + c1); }
#define RD_B(buf) \
  _Pragma("unroll") for (int jj = 0; jj < 4; jj++) { \
    const char* p_ = (const char*)&Bl[buf][0] + (size_t)(brow + jj * 16) * 128; \
    bfr[jj][0] = *(const bf16x8*)(p_ + c0); \
    bfr[jj][1] = *(const bf16x8*)(p_ + c1); }
#define MM(iofs, j0) \
  _Pragma("unroll") for (int ii = 0; ii < 4; ii++) \
  _Pragma("unroll") for (int jj = (j0); jj < (j0) + 2; jj++) { \
    acc[(iofs) + ii][jj] = __builtin_amdgcn_mfma_f32_16x16x32_bf16(af[ii][0], bfr[jj][0], acc[(iofs) + ii][jj], 0, 0, 0); \
    acc[(iofs) + ii][jj] = __builtin_amdgcn_mfma_f32_16x16x32_bf16(af[ii][1], bfr[jj][1], acc[(iofs) + ii][jj], 0, 0, 0); }
#define BARX __builtin_amdgcn_s_barrier()
#define LGKM0 do { asm volatile("s_waitcnt lgkmcnt(0)" ::: "memory"); \
                   __builtin_amdgcn_sched_barrier(0); } while (0)
#define PRI1 __builtin_amdgcn_s_setprio(1)
#define PRI0 __builtin_amdgcn_s_setprio(0)

#pragma unroll
  for (int q = 0; q < 4; q++) { STG_B(0, q, 0); }
#pragma unroll
  for (int q = 0; q < 4; q++) { STG_A(0, q, 0); }
#pragma unroll
  for (int q = 0; q < 4; q++) { STG_B(1, q, 1); }
#pragma unroll
  for (int q = 0; q < 4; q++) { STG_A(1, q, 1); }
  asm volatile("s_waitcnt vmcnt(8)" ::: "memory");
  BARX;

  bf16x8 af[4][2], bfr[4][2];

  for (int it = 0; it < NITER; it++) {
    const int kt0 = 2 * it;
    const bool st = (it + 1) < NITER;

    RD_A(0, 0); RD_B(0);
    BARX; LGKM0; PRI1; MM(0, 0); PRI0; BARX;
    if (st) { STG_B(0, 0, kt0 + 2); STG_B(0, 1, kt0 + 2); }
    PRI1; MM(0, 2); PRI0; BARX;
    RD_A(0, 1);
    if (st) { STG_B(0, 2, kt0 + 2); STG_B(0, 3, kt0 + 2); }
    BARX; LGKM0; PRI1; MM(4, 0); PRI0; BARX;
    if (st) { STG_A(0, 0, kt0 + 2); STG_A(0, 2, kt0 + 2); }
    PRI1; MM(4, 2); PRI0;
    asm volatile("s_waitcnt vmcnt(6)" ::: "memory");
    BARX;

    RD_A(1, 0); RD_B(1);
    if (st) { STG_A(0, 1, kt0 + 2); STG_A(0, 3, kt0 + 2); }
    BARX; LGKM0; PRI1; MM(0, 0); PRI0; BARX;
    if (st) { STG_B(1, 0, kt0 + 3); STG_B(1, 1, kt0 + 3); }
    PRI1; MM(0, 2); PRI0; BARX;
    RD_A(1, 1);
    if (st) { STG_B(1, 2, kt0 + 3); STG_B(1, 3, kt0 + 3); }
    BARX; LGKM0; PRI1; MM(4, 0); PRI0; BARX;
    if (st) { STG_A(1, 0, kt0 + 3); STG_A(1, 1, kt0 + 3);
              STG_A(1, 2, kt0 + 3); STG_A(1, 3, kt0 + 3); }
    PRI1; MM(4, 2); PRI0;
    asm volatile("s_waitcnt vmcnt(8)" ::: "memory");
    BARX;
  }

#undef STG_A
#undef STG_B
#undef RD_A
#undef RD_B
#undef MM
#undef BARX
#undef LGKM0
#undef PRI1
#undef PRI0

  float bs[4];
#pragma unroll
  for (int j = 0; j < 4; j++) bs[j] = bias[n0 + wn * 64 + j * 16 + l15];
#pragma unroll
  for (int i = 0; i < 8; i++)
#pragma unroll
    for (int j = 0; j < 4; j++)
#pragma unroll
      for (int rr = 0; rr < 4; rr++) {
        const int row = m0 + wm * 128 + i * 16 + kg * 4 + rr;
        const int col = n0 + wn * 64 + j * 16 + l15;
        C[(size_t)row * N + col] = (OutT)(acc[i][j][rr] + bs[j]);
      }
}

// ---------------- fused pool + rkv GEMV (round-9 version, bf16 weights) ----------------
__global__ __launch_bounds__(256) void pool_rkv_kernel(
    const bf16* __restrict__ xb, const bf16* __restrict__ rkv_wt,
    const float* __restrict__ rkv_b, bf16* __restrict__ rkvb)
{
  __shared__ float prow[1024];
  const int blk = blockIdx.x;              // b*64 + lt
  const int b = blk >> 6, lt = blk & 63;
  const int t = threadIdx.x;

  const bf16* px = xb + ((size_t)b * S_ + lt * 64) * 1024 + t * 4;
  float s0 = 0.f, s1 = 0.f, s2 = 0.f, s3 = 0.f;
#pragma unroll
  for (int c = 0; c < 64; c++) {
    bf16x4 v = *(const bf16x4*)(px + (size_t)c * 1024);
    s0 += (float)v[0]; s1 += (float)v[1]; s2 += (float)v[2]; s3 += (float)v[3];
  }
  prow[t * 4 + 0] = s0 * 0.015625f;
  prow[t * 4 + 1] = s1 * 0.015625f;
  prow[t * 4 + 2] = s2 * 0.015625f;
  prow[t * 4 + 3] = s3 * 0.015625f;
  __syncthreads();

  const int n = blockIdx.y * 256 + t;      // output column 0..511
  const bf16* wcol = rkv_wt + (size_t)n * 1024;
  float s = rkv_b[n];
#pragma unroll 4
  for (int k = 0; k < 1024; k += 8) {
    bf16x8 wv = *(const bf16x8*)(wcol + k);
#pragma unroll
    for (int j = 0; j < 8; j++) s += prow[k + j] * (float)wv[j];
  }
  rkvb[(size_t)blk * 512 + n] = (bf16)s;
}

// ---------------- latent attention (rq read from fused qkvrb) ----------------
__global__ __launch_bounds__(256) void latent_attn_kernel(
    const bf16* __restrict__ qkvrb, const bf16* __restrict__ rkvb,
    bf16* __restrict__ latout)
{
  __shared__ float rq_s[256];
  __shared__ float attn_s[4][64];
  const int blk = blockIdx.x;
  const int b = blk >> 12, s = blk & 4095;
  const int t = threadIdx.x;
  const int h = t >> 6, l = t & 63;
  const int cid = s >> 6;
  rq_s[t] = (float)qkvrb[((size_t)b * S_ + s) * QSTR + 3072 + t];
  __syncthreads();
  float val = -1e30f;
  if (l < cid) {
    const bf16* kr = rkvb + (size_t)(b * 64 + l) * 512 + h * 64;
    float sum = 0.f;
#pragma unroll
    for (int c = 0; c < 8; c++) {
      bf16x8 kv = *(const bf16x8*)(kr + c * 8);
#pragma unroll
      for (int j = 0; j < 8; j++) sum += rq_s[h * 64 + c * 8 + j] * (float)kv[j];
    }
    val = sum * 0.125f;
  }
  float mx = val;
#pragma unroll
  for (int off = 32; off; off >>= 1) mx = fmaxf(mx, __shfl_xor(mx, off));
  const float p = (l < cid) ? __expf(val - mx) : 0.f;
  float sm = p;
#pragma unroll
  for (int off = 32; off; off >>= 1) sm += __shfl_xor(sm, off);
  attn_s[h][l] = (sm > 0.f) ? p / sm : 0.f;
  __syncthreads();
  float o = 0.f;
  const bf16* vb = rkvb + (size_t)b * 64 * 512 + 256 + h * 64 + l;
  for (int lat = 0; lat < cid; lat++) o += attn_s[h][lat] * (float)vb[(size_t)lat * 512];
  latout[((size_t)b * S_ + s) * 256 + h * 64 + l] = (bf16)o;
}

// ---------------- local windowed attention + gate + mix (fused epilogue) ----------------
__global__ __launch_bounds__(256) void local_attn_gate(
    const bf16* __restrict__ qkv, const bf16* __restrict__ remote,
    const float* __restrict__ glw, const float* __restrict__ grw,
    bf16* __restrict__ mixedb)
{
  __shared__ __align__(16) bf16 Kl[128 * 72];
  __shared__ __align__(16) bf16 Vt[64 * 136];

  const int q0 = blockIdx.x * 128;
  const int h  = blockIdx.y;
  const int b  = blockIdx.z;
  const int t  = threadIdx.x;
  const int w  = t >> 6;
  const int l  = t & 63;
  const int g  = l >> 4;
  const int l15 = l & 15;

  const bf16* qbase = qkv + (size_t)b * S_ * QSTR + h * 64;
  const bf16* kbase = qbase + 1024;
  const bf16* vbase = qbase + 2048;

  bf16* PlW = &Kl[w * 32 * 72];

  const int kq = (t & 31) * 4;
  const int dh = (t >> 5) * 8;

  bf16x8 qf[2][2];
#pragma unroll
  for (int qg = 0; qg < 2; qg++)
#pragma unroll
    for (int db = 0; db < 2; db++)
      qf[qg][db] = *(const bf16x8*)(qbase + (size_t)(q0 + w * 32 + qg * 16 + l15) * QSTR + db * 32 + g * 8);

  float m_[2][4], l_[2][4];
  f32x4 accO[2][4];
#pragma unroll
  for (int qg = 0; qg < 2; qg++) {
#pragma unroll
    for (int r = 0; r < 4; r++) { m_[qg][r] = -1e30f; l_[qg][r] = 0.f; }
#pragma unroll
    for (int dt = 0; dt < 4; dt++) { f32x4 z = {0,0,0,0}; accO[qg][dt] = z; }
  }

  const int tstart = (q0 == 0) ? 1 : 0;

  bf16x8 kreg[4], vreg[4];
  {
    const int base = q0 - 128 + tstart * 128;
#pragma unroll
    for (int i = 0; i < 4; i++) {
      const int c = i * 256 + t;
      const int kk = c >> 3, dc = c & 7;
      kreg[i] = *(const bf16x8*)(kbase + (size_t)(base + kk) * QSTR + dc * 8);
    }
#pragma unroll
    for (int i = 0; i < 4; i++)
      vreg[i] = *(const bf16x8*)(vbase + (size_t)(base + kq + i) * QSTR + dh);
  }

  for (int tile = tstart; tile < 2; tile++) {
    __syncthreads();
#pragma unroll
    for (int i = 0; i < 4; i++) {
      const int c = i * 256 + t;
      const int kk = c >> 3, dc = c & 7;
      *(bf16x8*)&Kl[kk * 72 + dc * 8] = kreg[i];
    }
#pragma unroll
    for (int j = 0; j < 8; j++) {
      bf16x4 wv = {vreg[0][j], vreg[1][j], vreg[2][j], vreg[3][j]};
      *(bf16x4*)&Vt[(dh + j) * 136 + kq] = wv;
    }
    __syncthreads();
    if (tile == 0) {
#pragma unroll
      for (int i = 0; i < 4; i++) {
        const int c = i * 256 + t;
        const int kk = c >> 3, dc = c & 7;
        kreg[i] = *(const bf16x8*)(kbase + (size_t)(q0 + kk) * QSTR + dc * 8);
      }
#pragma unroll
      for (int i = 0; i < 4; i++)
        vreg[i] = *(const bf16x8*)(vbase + (size_t)(q0 + kq + i) * QSTR + dh);
    }

    const int kt_lo = (tile == 0) ? 2 * w : 0;
    const int kt_hi = (tile == 0) ? 8 : 2 * w + 2;
    const int nkt = kt_hi - kt_lo;

    f32x4 s[2][8];
#pragma unroll
    for (int qg = 0; qg < 2; qg++)
#pragma unroll
      for (int kk = 0; kk < 8; kk++) { f32x4 z = {0,0,0,0}; s[qg][kk] = z; }

#pragma unroll
    for (int kk = 0; kk < 8; kk++) {
      if (kk >= nkt) continue;
      const int kt = kt_lo + kk;
      const bf16x8 kf0 = *(const bf16x8*)&Kl[(kt * 16 + l15) * 72 + g * 8];
      const bf16x8 kf1 = *(const bf16x8*)&Kl[(kt * 16 + l15) * 72 + 32 + g * 8];
      s[0][kk] = __builtin_amdgcn_mfma_f32_16x16x32_bf16(qf[0][0], kf0, s[0][kk], 0, 0, 0);
      s[0][kk] = __builtin_amdgcn_mfma_f32_16x16x32_bf16(qf[0][1], kf1, s[0][kk], 0, 0, 0);
      s[1][kk] = __builtin_amdgcn_mfma_f32_16x16x32_bf16(qf[1][0], kf0, s[1][kk], 0, 0, 0);
      s[1][kk] = __builtin_amdgcn_mfma_f32_16x16x32_bf16(qf[1][1], kf1, s[1][kk], 0, 0, 0);
    }
    asm volatile("s_waitcnt lgkmcnt(0)" ::: "memory");
    __builtin_amdgcn_s_barrier();

#pragma unroll
    for (int qg = 0; qg < 2; qg++) {
#pragma unroll
      for (int kk = 0; kk < 8; kk++) {
        if (kk >= nkt) continue;
        const int kr = (kt_lo + kk) * 16 + l15;
#pragma unroll
        for (int r = 0; r < 4; r++) {
          const int qr = w * 32 + qg * 16 + g * 4 + r;
          const bool ok = (tile == 0) ? (kr >= qr) : (kr < qr);
          s[qg][kk][r] = ok ? s[qg][kk][r] * 0.125f : -1e9f;
        }
      }
      float corr[4];
#pragma unroll
      for (int r = 0; r < 4; r++) {
        float v = -1e30f;
#pragma unroll
        for (int kk = 0; kk < 8; kk++) { if (kk >= nkt) continue; v = fmaxf(v, s[qg][kk][r]); }
        v = fmaxf(v, __shfl_xor(v, 1));
        v = fmaxf(v, __shfl_xor(v, 2));
        v = fmaxf(v, __shfl_xor(v, 4));
        v = fmaxf(v, __shfl_xor(v, 8));
        const float mn = fmaxf(m_[qg][r], v);
        corr[r] = __expf(m_[qg][r] - mn);
        m_[qg][r] = mn;
      }
      float rs[4] = {0.f, 0.f, 0.f, 0.f};
#pragma unroll
      for (int kk = 0; kk < 8; kk++) {
        if (kk >= nkt) continue;
        const int kt = kt_lo + kk;
#pragma unroll
        for (int r = 0; r < 4; r++) {
          const float sv = s[qg][kk][r];
          const float p = (sv > -5e8f) ? __expf(sv - m_[qg][r]) : 0.f;
          rs[r] += p;
          PlW[(g * 4 + r) * 136 + kt * 16 + l15] = (bf16)p;
        }
      }
#pragma unroll
      for (int r = 0; r < 4; r++) {
        float v = rs[r];
        v += __shfl_xor(v, 1); v += __shfl_xor(v, 2);
        v += __shfl_xor(v, 4); v += __shfl_xor(v, 8);
        l_[qg][r] = l_[qg][r] * corr[r] + v;
#pragma unroll
        for (int dt = 0; dt < 4; dt++) accO[qg][dt][r] *= corr[r];
      }
      asm volatile("s_waitcnt lgkmcnt(0)" ::: "memory");
      __builtin_amdgcn_sched_barrier(0);
      const int kc_lo = (tile == 0) ? w : 0;
      const int kc_hi = (tile == 0) ? 4 : w + 1;
#pragma unroll
      for (int kc = 0; kc < 4; kc++) {
        if (kc < kc_lo || kc >= kc_hi) continue;
        const bf16x8 pa = *(const bf16x8*)&PlW[l15 * 136 + kc * 32 + g * 8];
#pragma unroll
        for (int dt = 0; dt < 4; dt++) {
          const bf16x8 vf = *(const bf16x8*)&Vt[(dt * 16 + l15) * 136 + kc * 32 + g * 8];
          accO[qg][dt] = __builtin_amdgcn_mfma_f32_16x16x32_bf16(pa, vf, accO[qg][dt], 0, 0, 0);
        }
      }
    }
  }

  // ---- fused gate + mix epilogue ----
  float glv[4], grv[4];
#pragma unroll
  for (int dt = 0; dt < 4; dt++) {
    glv[dt] = glw[dt * 16 + l15];
    grv[dt] = grw[dt * 16 + l15];
  }
  bf16* outp = mixedb + ((size_t)b * S_ + q0 + w * 32) * 1024 + h * 64;
  const bf16* rbase = remote + ((size_t)b * S_ + q0 + w * 32) * 1024 + h * 64;
#pragma unroll
  for (int qg = 0; qg < 2; qg++)
#pragma unroll
    for (int r = 0; r < 4; r++) {
      const int row = qg * 16 + g * 4 + r;
      const float inv = (l_[qg][r] > 0.f) ? 1.f / l_[qg][r] : 0.f;
      float lv[4], rv[4];
      float part = 0.f;
#pragma unroll
      for (int dt = 0; dt < 4; dt++) {
        lv[dt] = accO[qg][dt][r] * inv;
        rv[dt] = (float)rbase[(size_t)row * 1024 + dt * 16 + l15];
        part += lv[dt] * glv[dt] + rv[dt] * grv[dt];
      }
      part += __shfl_xor(part, 1);
      part += __shfl_xor(part, 2);
      part += __shfl_xor(part, 4);
      part += __shfl_xor(part, 8);
      const float gg = 1.f / (1.f + __expf(-part));
#pragma unroll
      for (int dt = 0; dt < 4; dt++)
        outp[(size_t)row * 1024 + dt * 16 + l15] = (bf16)(gg * lv[dt] + (1.f - gg) * rv[dt]);
    }
}

// ---------------- launch ----------------
extern "C" void kernel_launch(void* const* d_in, const int* in_sizes, int n_in,
                              void* d_out, int out_size, void* d_ws, size_t ws_size,
                              hipStream_t stream)
{
  const float* x      = (const float*)d_in[0];
  const float* qkv_w  = (const float*)d_in[1];
  const float* qkv_b  = (const float*)d_in[2];
  const float* rq_w   = (const float*)d_in[3];
  const float* rq_b   = (const float*)d_in[4];
  const float* rkv_w  = (const float*)d_in[5];
  const float* rkv_b  = (const float*)d_in[6];
  const float* rout_w = (const float*)d_in[7];
  const float* rout_b = (const float*)d_in[8];
  const float* out_w  = (const float*)d_in[9];
  const float* out_b  = (const float*)d_in[10];
  const float* gl_w   = (const float*)d_in[11];
  const float* gr_w   = (const float*)d_in[12];

  char* w = (char*)d_ws;
  bf16* qkvr_wt = (bf16*)w; w += (size_t)QSTR * 1024 * 2;
  bf16* rkv_wt  = (bf16*)w; w += (size_t)512 * 1024 * 2;
  bf16* rout_wt = (bf16*)w; w += (size_t)1024 * 256 * 2;
  bf16* out_wt  = (bf16*)w; w += (size_t)1024 * 1024 * 2;
  float* qkvr_b = (float*)w; w += (size_t)QSTR * 4;
  bf16* xb      = (bf16*)w; w += (size_t)B_ * S_ * 1024 * 2;
  bf16* qkvrb   = (bf16*)w; w += (size_t)B_ * S_ * QSTR * 2;
  bf16* rkvb    = (bf16*)w; w += (size_t)B_ * 64 * 512 * 2;
  bf16* latout  = (bf16*)w; w += (size_t)B_ * S_ * 256 * 2;
  bf16* remote  = (bf16*)w; w += (size_t)B_ * S_ * 1024 * 2;
  bf16* mixedb  = (bf16*)w; w += (size_t)B_ * S_ * 1024 * 2;

  prep_kernel<<<dim3(7169), 256, 0, stream>>>(qkv_w, rq_w, rkv_w, rout_w, out_w, x,
                                              qkv_b, rq_b,
                                              qkvr_wt, rkv_wt, rout_wt, out_wt, xb, qkvr_b);

  gemm8_kernel<bf16><<<dim3(32, 13), 512, 0, stream>>>(xb, qkvr_wt, qkvr_b, qkvrb, B_ * S_, QSTR, 1024);
  pool_rkv_kernel<<<dim3(128, 2), 256, 0, stream>>>(xb, rkv_wt, rkv_b, rkvb);
  latent_attn_kernel<<<dim3(B_ * S_), 256, 0, stream>>>(qkvrb, rkvb, latout);
  gemm_bias_kernel<bf16><<<dim3(64, 8), 256, 0, stream>>>(latout, rout_wt, rout_b, remote, B_ * S_, 1024, 256);
  local_attn_gate<<<dim3(S_ / 128, 16, B_), 256, 0, stream>>>(qkvrb, remote, gl_w, gr_w, mixedb);
  gemm_bias_kernel<float><<<dim3(64, 8), 256, 0, stream>>>(mixedb, out_wt, out_b, (float*)d_out, B_ * S_, 1024, 1024);
}

// Round 12
// 240.673 us; speedup vs baseline: 1.4424x; 1.0485x over previous
//
#include <hip/hip_runtime.h>

typedef __bf16 bf16;
typedef bf16 bf16x4 __attribute__((ext_vector_type(4)));
typedef bf16 bf16x8 __attribute__((ext_vector_type(8)));
typedef float f32x4 __attribute__((ext_vector_type(4)));

#define B_ 2
#define S_ 4096
#define D_ 1024
#define QSTR 3328   // fused qkv+rq row stride

__device__ __forceinline__ void gload_lds16(const void* g, void* l) {
  __builtin_amdgcn_global_load_lds((const __attribute__((address_space(1))) void*)g,
                                   (__attribute__((address_space(3))) void*)l, 16, 0, 0);
}

// ---------------- fused prep: 5 weight transposes + convert + fused bias ----------------
__device__ __forceinline__ void transpose_block(
    const float* __restrict__ in, bf16* __restrict__ out, int K, int N,
    int bx, int by, float (*tile)[33], int tx, int ty)
{
  const int nb = bx * 32, kb = by * 32;
#pragma unroll
  for (int j = 0; j < 4; j++)
    tile[ty + j * 8][tx] = in[(size_t)(kb + ty + j * 8) * N + nb + tx];
  __syncthreads();
#pragma unroll
  for (int j = 0; j < 4; j++)
    out[(size_t)(nb + ty + j * 8) * K + kb + tx] = (bf16)tile[tx][ty + j * 8];
}

__global__ __launch_bounds__(256) void prep_kernel(
    const float* __restrict__ qkv_w, const float* __restrict__ rq_w,
    const float* __restrict__ rkv_w, const float* __restrict__ rout_w,
    const float* __restrict__ out_w, const float* __restrict__ x,
    const float* __restrict__ qkv_b, const float* __restrict__ rq_b,
    bf16* __restrict__ qkvr_wt, bf16* __restrict__ rkv_wt,
    bf16* __restrict__ rout_wt, bf16* __restrict__ out_wt,
    bf16* __restrict__ xb, float* __restrict__ qkvr_b)
{
  __shared__ float tile[32][33];
  const int t = threadIdx.x;
  const int tx = t & 31, ty = t >> 5;
  int bid = blockIdx.x;
  if (bid < 3072) {
    transpose_block(qkv_w, qkvr_wt, 1024, 3072, bid % 96, bid / 96, tile, tx, ty);
    return;
  }
  bid -= 3072;
  if (bid < 256) {
    transpose_block(rq_w, qkvr_wt + (size_t)3072 * 1024, 1024, 256, bid % 8, bid / 8, tile, tx, ty);
    return;
  }
  bid -= 256;
  if (bid < 512) {
    transpose_block(rkv_w, rkv_wt, 1024, 512, bid % 16, bid / 16, tile, tx, ty);
    return;
  }
  bid -= 512;
  if (bid < 256) {
    transpose_block(rout_w, rout_wt, 256, 1024, bid % 32, bid / 32, tile, tx, ty);
    return;
  }
  bid -= 256;
  if (bid < 1024) {
    transpose_block(out_w, out_wt, 1024, 1024, bid % 32, bid / 32, tile, tx, ty);
    return;
  }
  bid -= 1024;
  if (bid < 2048) {
    const int n4 = B_ * S_ * 1024 / 4;
    for (int i = bid * 256 + t; i < n4; i += 2048 * 256) {
      const float4 v = ((const float4*)x)[i];
      bf16x4 o = {(bf16)v.x, (bf16)v.y, (bf16)v.z, (bf16)v.w};
      *(bf16x4*)&xb[i * 4] = o;
    }
    return;
  }
  {
    for (int i = t; i < 3072; i += 256) qkvr_b[i] = qkv_b[i];
    if (t < 256) qkvr_b[3072 + t] = rq_b[t];
  }
}

// ---------------- 128-tile GEMM (balanced grids for N<=1024 shapes) ----------------
template <typename OutT>
__global__ __launch_bounds__(256) void gemm_bias_kernel(
    const bf16* __restrict__ A, const bf16* __restrict__ Bt,
    const float* __restrict__ bias, OutT* __restrict__ C,
    int M, int N, int K)
{
  __shared__ __align__(16) bf16 Al[128 * 32];
  __shared__ __align__(16) bf16 Bl[128 * 32];
  const int m0 = blockIdx.x * 128;
  const int n0 = blockIdx.y * 128;
  const int t = threadIdx.x;
  const int lane = t & 63;
  const int wave = t >> 6;
  const int wr = (wave >> 1) * 64;
  const int wc = (wave & 1) * 64;
  const int r16 = lane & 15;
  const int kg = lane >> 4;

  f32x4 acc[4][4];
#pragma unroll
  for (int i = 0; i < 4; i++)
#pragma unroll
    for (int j = 0; j < 4; j++) {
      f32x4 z = {0.f, 0.f, 0.f, 0.f};
      acc[i][j] = z;
    }

  for (int k0 = 0; k0 < K; k0 += 32) {
    __syncthreads();
#pragma unroll
    for (int i = 0; i < 2; i++) {
      const int o = i * 4096 + wave * 1024 + lane * 16;
      const int r = o >> 6;
      const int cb = o & 63;
      gload_lds16((const char*)(A + (size_t)(m0 + r) * K + k0) + cb,
                  (char*)Al + i * 4096 + wave * 1024);
      gload_lds16((const char*)(Bt + (size_t)(n0 + r) * K + k0) + cb,
                  (char*)Bl + i * 4096 + wave * 1024);
    }
    __syncthreads();
    bf16x8 a[4], b[4];
#pragma unroll
    for (int i = 0; i < 4; i++)
      a[i] = *(const bf16x8*)&Al[(wr + i * 16 + r16) * 32 + kg * 8];
#pragma unroll
    for (int i = 0; i < 4; i++)
      b[i] = *(const bf16x8*)&Bl[(wc + i * 16 + r16) * 32 + kg * 8];
#pragma unroll
    for (int i = 0; i < 4; i++)
#pragma unroll
      for (int j = 0; j < 4; j++)
        acc[i][j] = __builtin_amdgcn_mfma_f32_16x16x32_bf16(a[i], b[j], acc[i][j], 0, 0, 0);
  }

  float bs[4];
#pragma unroll
  for (int j = 0; j < 4; j++) bs[j] = bias[n0 + wc + j * 16 + r16];
#pragma unroll
  for (int i = 0; i < 4; i++)
#pragma unroll
    for (int j = 0; j < 4; j++)
#pragma unroll
      for (int r = 0; r < 4; r++) {
        const int row = m0 + wr + i * 16 + kg * 4 + r;
        const int col = n0 + wc + j * 16 + r16;
        C[(size_t)row * N + col] = (OutT)(acc[i][j][r] + bs[j]);
      }
}

// ---------------- 256x256 8-phase GEMM (frozen) ----------------
template <typename OutT>
__global__ __launch_bounds__(512, 1) void gemm8_kernel(
    const bf16* __restrict__ A, const bf16* __restrict__ Bt,
    const float* __restrict__ bias, OutT* __restrict__ C,
    int M, int N, int K)
{
  __shared__ __align__(16) bf16 Al[2][256 * 64];
  __shared__ __align__(16) bf16 Bl[2][256 * 64];

  const int nbx = gridDim.x;
  const int nwg = nbx * gridDim.y;
  int bid = blockIdx.y * nbx + blockIdx.x;
  bid = (bid & 7) * (nwg >> 3) + (bid >> 3);   // XCD swizzle (nwg % 8 == 0)
  const int m0 = (bid % nbx) * 256;
  const int n0 = (bid / nbx) * 256;

  const int t = threadIdx.x;
  const int lane = t & 63;
  const int w = t >> 6;
  const int wm = w >> 2;
  const int wn = w & 3;
  const int l15 = lane & 15;
  const int kg = lane >> 4;

  const int srow = t >> 3;
  const int schunk = (t & 7) ^ (srow & 7);
  const bf16* Aaddr = A + (size_t)(m0 + srow) * K + schunk * 8;
  const bf16* Baddr = Bt + (size_t)(n0 + srow) * K + schunk * 8;

  const int NT = K >> 6;
  const int NITER = NT >> 1;

  const int arow = wm * 128 + l15;
  const int brow = wn * 64 + l15;
  const int c0 = (kg ^ (l15 & 7)) * 16;
  const int c1 = ((4 + kg) ^ (l15 & 7)) * 16;

  f32x4 acc[8][4];
#pragma unroll
  for (int i = 0; i < 8; i++)
#pragma unroll
    for (int j = 0; j < 4; j++) { f32x4 z = {0, 0, 0, 0}; acc[i][j] = z; }

#define STG_A(buf, q, kt) gload_lds16(Aaddr + (size_t)(q) * 64 * K + (kt) * 64, \
                                      (char*)&Al[buf][0] + (q) * 8192 + w * 1024)
#define STG_B(buf, q, kt) gload_lds16(Baddr + (size_t)(q) * 64 * K + (kt) * 64, \
                                      (char*)&Bl[buf][0] + (q) * 8192 + w * 1024)
#define RD_A(buf, aq) \
  _Pragma("unroll") for (int ii = 0; ii < 4; ii++) { \
    const char* p_ = (const char*)&Al[buf][0] + (size_t)(arow + (aq) * 64 + ii * 16) * 128; \
    af[ii][0] = *(const bf16x8*)(p_ + c0); \
    af[ii][1] = *(const bf16x8*)(p_ + c1); }
#define RD_B(buf) \
  _Pragma("unroll") for (int jj = 0; jj < 4; jj++) { \
    const char* p_ = (const char*)&Bl[buf][0] + (size_t)(brow + jj * 16) * 128; \
    bfr[jj][0] = *(const bf16x8*)(p_ + c0); \
    bfr[jj][1] = *(const bf16x8*)(p_ + c1); }
#define MM(iofs, j0) \
  _Pragma("unroll") for (int ii = 0; ii < 4; ii++) \
  _Pragma("unroll") for (int jj = (j0); jj < (j0) + 2; jj++) { \
    acc[(iofs) + ii][jj] = __builtin_amdgcn_mfma_f32_16x16x32_bf16(af[ii][0], bfr[jj][0], acc[(iofs) + ii][jj], 0, 0, 0); \
    acc[(iofs) + ii][jj] = __builtin_amdgcn_mfma_f32_16x16x32_bf16(af[ii][1], bfr[jj][1], acc[(iofs) + ii][jj], 0, 0, 0); }
#define BARX __builtin_amdgcn_s_barrier()
#define LGKM0 do { asm volatile("s_waitcnt lgkmcnt(0)" ::: "memory"); \
                   __builtin_amdgcn_sched_barrier(0); } while (0)
#define PRI1 __builtin_amdgcn_s_setprio(1)
#define PRI0 __builtin_amdgcn_s_setprio(0)

#pragma unroll
  for (int q = 0; q < 4; q++) { STG_B(0, q, 0); }
#pragma unroll
  for (int q = 0; q < 4; q++) { STG_A(0, q, 0); }
#pragma unroll
  for (int q = 0; q < 4; q++) { STG_B(1, q, 1); }
#pragma unroll
  for (int q = 0; q < 4; q++) { STG_A(1, q, 1); }
  asm volatile("s_waitcnt vmcnt(8)" ::: "memory");
  BARX;

  bf16x8 af[4][2], bfr[4][2];

  for (int it = 0; it < NITER; it++) {
    const int kt0 = 2 * it;
    const bool st = (it + 1) < NITER;

    RD_A(0, 0); RD_B(0);
    BARX; LGKM0; PRI1; MM(0, 0); PRI0; BARX;
    if (st) { STG_B(0, 0, kt0 + 2); STG_B(0, 1, kt0 + 2); }
    PRI1; MM(0, 2); PRI0; BARX;
    RD_A(0, 1);
    if (st) { STG_B(0, 2, kt0 + 2); STG_B(0, 3, kt0 + 2); }
    BARX; LGKM0; PRI1; MM(4, 0); PRI0; BARX;
    if (st) { STG_A(0, 0, kt0 + 2); STG_A(0, 2, kt0 + 2); }
    PRI1; MM(4, 2); PRI0;
    asm volatile("s_waitcnt vmcnt(6)" ::: "memory");
    BARX;

    RD_A(1, 0); RD_B(1);
    if (st) { STG_A(0, 1, kt0 + 2); STG_A(0, 3, kt0 + 2); }
    BARX; LGKM0; PRI1; MM(0, 0); PRI0; BARX;
    if (st) { STG_B(1, 0, kt0 + 3); STG_B(1, 1, kt0 + 3); }
    PRI1; MM(0, 2); PRI0; BARX;
    RD_A(1, 1);
    if (st) { STG_B(1, 2, kt0 + 3); STG_B(1, 3, kt0 + 3); }
    BARX; LGKM0; PRI1; MM(4, 0); PRI0; BARX;
    if (st) { STG_A(1, 0, kt0 + 3); STG_A(1, 1, kt0 + 3);
              STG_A(1, 2, kt0 + 3); STG_A(1, 3, kt0 + 3); }
    PRI1; MM(4, 2); PRI0;
    asm volatile("s_waitcnt vmcnt(8)" ::: "memory");
    BARX;
  }

#undef STG_A
#undef STG_B
#undef RD_A
#undef RD_B
#undef MM
#undef BARX
#undef LGKM0
#undef PRI1
#undef PRI0

  float bs[4];
#pragma unroll
  for (int j = 0; j < 4; j++) bs[j] = bias[n0 + wn * 64 + j * 16 + l15];
#pragma unroll
  for (int i = 0; i < 8; i++)
#pragma unroll
    for (int j = 0; j < 4; j++)
#pragma unroll
      for (int rr = 0; rr < 4; rr++) {
        const int row = m0 + wm * 128 + i * 16 + kg * 4 + rr;
        const int col = n0 + wn * 64 + j * 16 + l15;
        C[(size_t)row * N + col] = (OutT)(acc[i][j][rr] + bs[j]);
      }
}

// ---------------- fused pool + rkv GEMV ----------------
__global__ __launch_bounds__(256) void pool_rkv_kernel(
    const bf16* __restrict__ xb, const bf16* __restrict__ rkv_wt,
    const float* __restrict__ rkv_b, bf16* __restrict__ rkvb)
{
  __shared__ float prow[1024];
  const int blk = blockIdx.x;
  const int b = blk >> 6, lt = blk & 63;
  const int t = threadIdx.x;

  const bf16* px = xb + ((size_t)b * S_ + lt * 64) * 1024 + t * 4;
  float s0 = 0.f, s1 = 0.f, s2 = 0.f, s3 = 0.f;
#pragma unroll
  for (int c = 0; c < 64; c++) {
    bf16x4 v = *(const bf16x4*)(px + (size_t)c * 1024);
    s0 += (float)v[0]; s1 += (float)v[1]; s2 += (float)v[2]; s3 += (float)v[3];
  }
  prow[t * 4 + 0] = s0 * 0.015625f;
  prow[t * 4 + 1] = s1 * 0.015625f;
  prow[t * 4 + 2] = s2 * 0.015625f;
  prow[t * 4 + 3] = s3 * 0.015625f;
  __syncthreads();

  const int n = blockIdx.y * 256 + t;
  const bf16* wcol = rkv_wt + (size_t)n * 1024;
  float s = rkv_b[n];
#pragma unroll 4
  for (int k = 0; k < 1024; k += 8) {
    bf16x8 wv = *(const bf16x8*)(wcol + k);
#pragma unroll
    for (int j = 0; j < 8; j++) s += prow[k + j] * (float)wv[j];
  }
  rkvb[(size_t)blk * 512 + n] = (bf16)s;
}

// ---------------- latent attention ----------------
__global__ __launch_bounds__(256) void latent_attn_kernel(
    const bf16* __restrict__ qkvrb, const bf16* __restrict__ rkvb,
    bf16* __restrict__ latout)
{
  __shared__ float rq_s[256];
  __shared__ float attn_s[4][64];
  const int blk = blockIdx.x;
  const int b = blk >> 12, s = blk & 4095;
  const int t = threadIdx.x;
  const int h = t >> 6, l = t & 63;
  const int cid = s >> 6;
  rq_s[t] = (float)qkvrb[((size_t)b * S_ + s) * QSTR + 3072 + t];
  __syncthreads();
  float val = -1e30f;
  if (l < cid) {
    const bf16* kr = rkvb + (size_t)(b * 64 + l) * 512 + h * 64;
    float sum = 0.f;
#pragma unroll
    for (int c = 0; c < 8; c++) {
      bf16x8 kv = *(const bf16x8*)(kr + c * 8);
#pragma unroll
      for (int j = 0; j < 8; j++) sum += rq_s[h * 64 + c * 8 + j] * (float)kv[j];
    }
    val = sum * 0.125f;
  }
  float mx = val;
#pragma unroll
  for (int off = 32; off; off >>= 1) mx = fmaxf(mx, __shfl_xor(mx, off));
  const float p = (l < cid) ? __expf(val - mx) : 0.f;
  float sm = p;
#pragma unroll
  for (int off = 32; off; off >>= 1) sm += __shfl_xor(sm, off);
  attn_s[h][l] = (sm > 0.f) ? p / sm : 0.f;
  __syncthreads();
  float o = 0.f;
  const bf16* vb = rkvb + (size_t)b * 64 * 512 + 256 + h * 64 + l;
  for (int lat = 0; lat < cid; lat++) o += attn_s[h][lat] * (float)vb[(size_t)lat * 512];
  latout[((size_t)b * S_ + s) * 256 + h * 64 + l] = (bf16)o;
}

// ---------------- local attn + gate, v3: balanced qg pairing {w, 7-w} ----------------
// Wave w owns qg tiles j = w and j = 7-w. Per-qg exact chunk-aligned kt ranges
// balance per-tile QK/softmax/PV across waves (10 kt/wave/tile vs prior max 16).
// Separate per-wave P buffer (no Kl alias) -> no post-QK barrier.
__global__ __launch_bounds__(256) void local_attn_gate(
    const bf16* __restrict__ qkv, const bf16* __restrict__ remote,
    const float* __restrict__ glw, const float* __restrict__ grw,
    bf16* __restrict__ mixedb)
{
  __shared__ __align__(16) bf16 Kl[128 * 72];
  __shared__ __align__(16) bf16 Vt[64 * 136];
  __shared__ __align__(16) bf16 Pl[4][16 * 136];

  const int q0 = blockIdx.x * 128;
  const int h  = blockIdx.y;
  const int b  = blockIdx.z;
  const int t  = threadIdx.x;
  const int w  = t >> 6;
  const int l  = t & 63;
  const int g  = l >> 4;
  const int l15 = l & 15;

  const bf16* qbase = qkv + (size_t)b * S_ * QSTR + h * 64;
  const bf16* kbase = qbase + 1024;
  const bf16* vbase = qbase + 2048;

  bf16* PlW = &Pl[w][0];

  const int kq = (t & 31) * 4;
  const int dh = (t >> 5) * 8;

  // qg tiles owned by this wave: slot 0 -> j=w, slot 1 -> j=7-w
  bf16x8 qf[2][2];
#pragma unroll
  for (int sl = 0; sl < 2; sl++) {
    const int j = sl ? 7 - w : w;
#pragma unroll
    for (int db = 0; db < 2; db++)
      qf[sl][db] = *(const bf16x8*)(qbase + (size_t)(q0 + j * 16 + l15) * QSTR + db * 32 + g * 8);
  }

  float m_[2][4], l_[2][4];
  f32x4 accO[2][4];
#pragma unroll
  for (int sl = 0; sl < 2; sl++) {
#pragma unroll
    for (int r = 0; r < 4; r++) { m_[sl][r] = -1e30f; l_[sl][r] = 0.f; }
#pragma unroll
    for (int dt = 0; dt < 4; dt++) { f32x4 z = {0,0,0,0}; accO[sl][dt] = z; }
  }

  const int tstart = (q0 == 0) ? 1 : 0;

  bf16x8 kreg[4], vreg[4];
  {
    const int base = q0 - 128 + tstart * 128;
#pragma unroll
    for (int i = 0; i < 4; i++) {
      const int c = i * 256 + t;
      const int kk = c >> 3, dc = c & 7;
      kreg[i] = *(const bf16x8*)(kbase + (size_t)(base + kk) * QSTR + dc * 8);
    }
#pragma unroll
    for (int i = 0; i < 4; i++)
      vreg[i] = *(const bf16x8*)(vbase + (size_t)(base + kq + i) * QSTR + dh);
  }

  for (int tile = tstart; tile < 2; tile++) {
    __syncthreads();
#pragma unroll
    for (int i = 0; i < 4; i++) {
      const int c = i * 256 + t;
      const int kk = c >> 3, dc = c & 7;
      *(bf16x8*)&Kl[kk * 72 + dc * 8] = kreg[i];
    }
#pragma unroll
    for (int j = 0; j < 8; j++) {
      bf16x4 wv = {vreg[0][j], vreg[1][j], vreg[2][j], vreg[3][j]};
      *(bf16x4*)&Vt[(dh + j) * 136 + kq] = wv;
    }
    __syncthreads();
    if (tile == 0) {
#pragma unroll
      for (int i = 0; i < 4; i++) {
        const int c = i * 256 + t;
        const int kk = c >> 3, dc = c & 7;
        kreg[i] = *(const bf16x8*)(kbase + (size_t)(q0 + kk) * QSTR + dc * 8);
      }
#pragma unroll
      for (int i = 0; i < 4; i++)
        vreg[i] = *(const bf16x8*)(vbase + (size_t)(q0 + kq + i) * QSTR + dh);
    }

#pragma unroll
    for (int sl = 0; sl < 2; sl++) {
      const int j = sl ? 7 - w : w;
      const int lo = (tile == 0) ? (j & ~1) : 0;
      const int hi = (tile == 0) ? 8 : ((j & ~1) + 2);

      f32x4 s[8];
#pragma unroll
      for (int kk = 0; kk < 8; kk++) {
        if (kk < lo || kk >= hi) continue;
        f32x4 z = {0,0,0,0};
        s[kk] = z;
        const bf16x8 kf0 = *(const bf16x8*)&Kl[(kk * 16 + l15) * 72 + g * 8];
        const bf16x8 kf1 = *(const bf16x8*)&Kl[(kk * 16 + l15) * 72 + 32 + g * 8];
        s[kk] = __builtin_amdgcn_mfma_f32_16x16x32_bf16(qf[sl][0], kf0, s[kk], 0, 0, 0);
        s[kk] = __builtin_amdgcn_mfma_f32_16x16x32_bf16(qf[sl][1], kf1, s[kk], 0, 0, 0);
      }
      // mask + scale
#pragma unroll
      for (int kk = 0; kk < 8; kk++) {
        if (kk < lo || kk >= hi) continue;
        const int kr = kk * 16 + l15;
#pragma unroll
        for (int r = 0; r < 4; r++) {
          const int qr = j * 16 + g * 4 + r;
          const bool ok = (tile == 0) ? (kr >= qr) : (kr < qr);
          s[kk][r] = ok ? s[kk][r] * 0.125f : -1e9f;
        }
      }
      float corr[4];
#pragma unroll
      for (int r = 0; r < 4; r++) {
        float v = -1e30f;
#pragma unroll
        for (int kk = 0; kk < 8; kk++) { if (kk < lo || kk >= hi) continue; v = fmaxf(v, s[kk][r]); }
        v = fmaxf(v, __shfl_xor(v, 1));
        v = fmaxf(v, __shfl_xor(v, 2));
        v = fmaxf(v, __shfl_xor(v, 4));
        v = fmaxf(v, __shfl_xor(v, 8));
        const float mn = fmaxf(m_[sl][r], v);
        corr[r] = __expf(m_[sl][r] - mn);
        m_[sl][r] = mn;
      }
      float rs[4] = {0.f, 0.f, 0.f, 0.f};
#pragma unroll
      for (int kk = 0; kk < 8; kk++) {
        if (kk < lo || kk >= hi) continue;
#pragma unroll
        for (int r = 0; r < 4; r++) {
          const float sv = s[kk][r];
          const float p = (sv > -5e8f) ? __expf(sv - m_[sl][r]) : 0.f;
          rs[r] += p;
          PlW[(g * 4 + r) * 136 + kk * 16 + l15] = (bf16)p;
        }
      }
#pragma unroll
      for (int r = 0; r < 4; r++) {
        float v = rs[r];
        v += __shfl_xor(v, 1); v += __shfl_xor(v, 2);
        v += __shfl_xor(v, 4); v += __shfl_xor(v, 8);
        l_[sl][r] = l_[sl][r] * corr[r] + v;
#pragma unroll
        for (int dt = 0; dt < 4; dt++) accO[sl][dt][r] *= corr[r];
      }
      asm volatile("s_waitcnt lgkmcnt(0)" ::: "memory");
      __builtin_amdgcn_sched_barrier(0);
      const int clo = (tile == 0) ? (j >> 1) : 0;
      const int chi = (tile == 0) ? 4 : ((j >> 1) + 1);
#pragma unroll
      for (int kc = 0; kc < 4; kc++) {
        if (kc < clo || kc >= chi) continue;
        const bf16x8 pa = *(const bf16x8*)&PlW[l15 * 136 + kc * 32 + g * 8];
#pragma unroll
        for (int dt = 0; dt < 4; dt++) {
          const bf16x8 vf = *(const bf16x8*)&Vt[(dt * 16 + l15) * 136 + kc * 32 + g * 8];
          accO[sl][dt] = __builtin_amdgcn_mfma_f32_16x16x32_bf16(pa, vf, accO[sl][dt], 0, 0, 0);
        }
      }
    }
  }

  // ---- fused gate + mix epilogue ----
  float glv[4], grv[4];
#pragma unroll
  for (int dt = 0; dt < 4; dt++) {
    glv[dt] = glw[dt * 16 + l15];
    grv[dt] = grw[dt * 16 + l15];
  }
  bf16* outp = mixedb + ((size_t)b * S_ + q0) * 1024 + h * 64;
  const bf16* rbase = remote + ((size_t)b * S_ + q0) * 1024 + h * 64;
#pragma unroll
  for (int sl = 0; sl < 2; sl++) {
    const int j = sl ? 7 - w : w;
#pragma unroll
    for (int r = 0; r < 4; r++) {
      const int row = j * 16 + g * 4 + r;
      const float inv = (l_[sl][r] > 0.f) ? 1.f / l_[sl][r] : 0.f;
      float lv[4], rv[4];
      float part = 0.f;
#pragma unroll
      for (int dt = 0; dt < 4; dt++) {
        lv[dt] = accO[sl][dt][r] * inv;
        rv[dt] = (float)rbase[(size_t)row * 1024 + dt * 16 + l15];
        part += lv[dt] * glv[dt] + rv[dt] * grv[dt];
      }
      part += __shfl_xor(part, 1);
      part += __shfl_xor(part, 2);
      part += __shfl_xor(part, 4);
      part += __shfl_xor(part, 8);
      const float gg = 1.f / (1.f + __expf(-part));
#pragma unroll
      for (int dt = 0; dt < 4; dt++)
        outp[(size_t)row * 1024 + dt * 16 + l15] = (bf16)(gg * lv[dt] + (1.f - gg) * rv[dt]);
    }
  }
}

// ---------------- launch ----------------
extern "C" void kernel_launch(void* const* d_in, const int* in_sizes, int n_in,
                              void* d_out, int out_size, void* d_ws, size_t ws_size,
                              hipStream_t stream)
{
  const float* x      = (const float*)d_in[0];
  const float* qkv_w  = (const float*)d_in[1];
  const float* qkv_b  = (const float*)d_in[2];
  const float* rq_w   = (const float*)d_in[3];
  const float* rq_b   = (const float*)d_in[4];
  const float* rkv_w  = (const float*)d_in[5];
  const float* rkv_b  = (const float*)d_in[6];
  const float* rout_w = (const float*)d_in[7];
  const float* rout_b = (const float*)d_in[8];
  const float* out_w  = (const float*)d_in[9];
  const float* out_b  = (const float*)d_in[10];
  const float* gl_w   = (const float*)d_in[11];
  const float* gr_w   = (const float*)d_in[12];

  char* w = (char*)d_ws;
  bf16* qkvr_wt = (bf16*)w; w += (size_t)QSTR * 1024 * 2;
  bf16* rkv_wt  = (bf16*)w; w += (size_t)512 * 1024 * 2;
  bf16* rout_wt = (bf16*)w; w += (size_t)1024 * 256 * 2;
  bf16* out_wt  = (bf16*)w; w += (size_t)1024 * 1024 * 2;
  float* qkvr_b = (float*)w; w += (size_t)QSTR * 4;
  bf16* xb      = (bf16*)w; w += (size_t)B_ * S_ * 1024 * 2;
  bf16* qkvrb   = (bf16*)w; w += (size_t)B_ * S_ * QSTR * 2;
  bf16* rkvb    = (bf16*)w; w += (size_t)B_ * 64 * 512 * 2;
  bf16* latout  = (bf16*)w; w += (size_t)B_ * S_ * 256 * 2;
  bf16* remote  = (bf16*)w; w += (size_t)B_ * S_ * 1024 * 2;
  bf16* mixedb  = (bf16*)w; w += (size_t)B_ * S_ * 1024 * 2;

  prep_kernel<<<dim3(7169), 256, 0, stream>>>(qkv_w, rq_w, rkv_w, rout_w, out_w, x,
                                              qkv_b, rq_b,
                                              qkvr_wt, rkv_wt, rout_wt, out_wt, xb, qkvr_b);

  gemm8_kernel<bf16><<<dim3(32, 13), 512, 0, stream>>>(xb, qkvr_wt, qkvr_b, qkvrb, B_ * S_, QSTR, 1024);
  pool_rkv_kernel<<<dim3(128, 2), 256, 0, stream>>>(xb, rkv_wt, rkv_b, rkvb);
  latent_attn_kernel<<<dim3(B_ * S_), 256, 0, stream>>>(qkvrb, rkvb, latout);
  gemm_bias_kernel<bf16><<<dim3(64, 8), 256, 0, stream>>>(latout, rout_wt, rout_b, remote, B_ * S_, 1024, 256);
  local_attn_gate<<<dim3(S_ / 128, 16, B_), 256, 0, stream>>>(qkvrb, remote, gl_w, gr_w, mixedb);
  gemm_bias_kernel<float><<<dim3(64, 8), 256, 0, stream>>>(mixedb, out_wt, out_b, (float*)d_out, B_ * S_, 1024, 1024);
}

// Round 13
// 216.503 us; speedup vs baseline: 1.6034x; 1.1116x over previous
//
#include <hip/hip_runtime.h>

typedef __bf16 bf16;
typedef bf16 bf16x4 __attribute__((ext_vector_type(4)));
typedef bf16 bf16x8 __attribute__((ext_vector_type(8)));
typedef float f32x4 __attribute__((ext_vector_type(4)));

#define B_ 2
#define S_ 4096
#define D_ 1024
#define QSTR 3328   // fused qkv+rq row stride

__device__ __forceinline__ void gload_lds16(const void* g, void* l) {
  __builtin_amdgcn_global_load_lds((const __attribute__((address_space(1))) void*)g,
                                   (__attribute__((address_space(3))) void*)l, 16, 0, 0);
}

// ---------------- fused prep: 5 weight transposes + convert + fused bias ----------------
__device__ __forceinline__ void transpose_block(
    const float* __restrict__ in, bf16* __restrict__ out, int K, int N,
    int bx, int by, float (*tile)[33], int tx, int ty)
{
  const int nb = bx * 32, kb = by * 32;
#pragma unroll
  for (int j = 0; j < 4; j++)
    tile[ty + j * 8][tx] = in[(size_t)(kb + ty + j * 8) * N + nb + tx];
  __syncthreads();
#pragma unroll
  for (int j = 0; j < 4; j++)
    out[(size_t)(nb + ty + j * 8) * K + kb + tx] = (bf16)tile[tx][ty + j * 8];
}

__global__ __launch_bounds__(256) void prep_kernel(
    const float* __restrict__ qkv_w, const float* __restrict__ rq_w,
    const float* __restrict__ rkv_w, const float* __restrict__ rout_w,
    const float* __restrict__ out_w, const float* __restrict__ x,
    const float* __restrict__ qkv_b, const float* __restrict__ rq_b,
    bf16* __restrict__ qkvr_wt, bf16* __restrict__ rkv_wt,
    bf16* __restrict__ rout_wt, bf16* __restrict__ out_wt,
    bf16* __restrict__ xb, float* __restrict__ qkvr_b)
{
  __shared__ float tile[32][33];
  const int t = threadIdx.x;
  const int tx = t & 31, ty = t >> 5;
  int bid = blockIdx.x;
  if (bid < 3072) {
    transpose_block(qkv_w, qkvr_wt, 1024, 3072, bid % 96, bid / 96, tile, tx, ty);
    return;
  }
  bid -= 3072;
  if (bid < 256) {
    transpose_block(rq_w, qkvr_wt + (size_t)3072 * 1024, 1024, 256, bid % 8, bid / 8, tile, tx, ty);
    return;
  }
  bid -= 256;
  if (bid < 512) {
    transpose_block(rkv_w, rkv_wt, 1024, 512, bid % 16, bid / 16, tile, tx, ty);
    return;
  }
  bid -= 512;
  if (bid < 256) {
    transpose_block(rout_w, rout_wt, 256, 1024, bid % 32, bid / 32, tile, tx, ty);
    return;
  }
  bid -= 256;
  if (bid < 1024) {
    transpose_block(out_w, out_wt, 1024, 1024, bid % 32, bid / 32, tile, tx, ty);
    return;
  }
  bid -= 1024;
  if (bid < 2048) {
    const int n4 = B_ * S_ * 1024 / 4;
    for (int i = bid * 256 + t; i < n4; i += 2048 * 256) {
      const float4 v = ((const float4*)x)[i];
      bf16x4 o = {(bf16)v.x, (bf16)v.y, (bf16)v.z, (bf16)v.w};
      *(bf16x4*)&xb[i * 4] = o;
    }
    return;
  }
  {
    for (int i = t; i < 3072; i += 256) qkvr_b[i] = qkv_b[i];
    if (t < 256) qkvr_b[3072 + t] = rq_b[t];
  }
}

// ---------------- 128-tile GEMM (balanced grids for N<=1024 shapes) ----------------
template <typename OutT>
__global__ __launch_bounds__(256) void gemm_bias_kernel(
    const bf16* __restrict__ A, const bf16* __restrict__ Bt,
    const float* __restrict__ bias, OutT* __restrict__ C,
    int M, int N, int K)
{
  __shared__ __align__(16) bf16 Al[128 * 32];
  __shared__ __align__(16) bf16 Bl[128 * 32];
  const int m0 = blockIdx.x * 128;
  const int n0 = blockIdx.y * 128;
  const int t = threadIdx.x;
  const int lane = t & 63;
  const int wave = t >> 6;
  const int wr = (wave >> 1) * 64;
  const int wc = (wave & 1) * 64;
  const int r16 = lane & 15;
  const int kg = lane >> 4;

  f32x4 acc[4][4];
#pragma unroll
  for (int i = 0; i < 4; i++)
#pragma unroll
    for (int j = 0; j < 4; j++) {
      f32x4 z = {0.f, 0.f, 0.f, 0.f};
      acc[i][j] = z;
    }

  for (int k0 = 0; k0 < K; k0 += 32) {
    __syncthreads();
#pragma unroll
    for (int i = 0; i < 2; i++) {
      const int o = i * 4096 + wave * 1024 + lane * 16;
      const int r = o >> 6;
      const int cb = o & 63;
      gload_lds16((const char*)(A + (size_t)(m0 + r) * K + k0) + cb,
                  (char*)Al + i * 4096 + wave * 1024);
      gload_lds16((const char*)(Bt + (size_t)(n0 + r) * K + k0) + cb,
                  (char*)Bl + i * 4096 + wave * 1024);
    }
    __syncthreads();
    bf16x8 a[4], b[4];
#pragma unroll
    for (int i = 0; i < 4; i++)
      a[i] = *(const bf16x8*)&Al[(wr + i * 16 + r16) * 32 + kg * 8];
#pragma unroll
    for (int i = 0; i < 4; i++)
      b[i] = *(const bf16x8*)&Bl[(wc + i * 16 + r16) * 32 + kg * 8];
#pragma unroll
    for (int i = 0; i < 4; i++)
#pragma unroll
      for (int j = 0; j < 4; j++)
        acc[i][j] = __builtin_amdgcn_mfma_f32_16x16x32_bf16(a[i], b[j], acc[i][j], 0, 0, 0);
  }

  float bs[4];
#pragma unroll
  for (int j = 0; j < 4; j++) bs[j] = bias[n0 + wc + j * 16 + r16];
#pragma unroll
  for (int i = 0; i < 4; i++)
#pragma unroll
    for (int j = 0; j < 4; j++)
#pragma unroll
      for (int r = 0; r < 4; r++) {
        const int row = m0 + wr + i * 16 + kg * 4 + r;
        const int col = n0 + wc + j * 16 + r16;
        C[(size_t)row * N + col] = (OutT)(acc[i][j][r] + bs[j]);
      }
}

// ---------------- 256x256 8-phase GEMM, UNPINNED (reads overlap MFMA) ----------------
// Same stage/vmcnt ledger as before; removed lgkmcnt(0)+sched_barrier pins between
// ds_reads and MFMA so the compiler's partial lgkm waits let MFMA start as frags land.
// One trailing barrier per phase; lgkm drain only at ends of read-phases.
template <typename OutT>
__global__ __launch_bounds__(512, 1) void gemm8_kernel(
    const bf16* __restrict__ A, const bf16* __restrict__ Bt,
    const float* __restrict__ bias, OutT* __restrict__ C,
    int M, int N, int K)
{
  __shared__ __align__(16) bf16 Al[2][256 * 64];
  __shared__ __align__(16) bf16 Bl[2][256 * 64];

  const int nbx = gridDim.x;
  const int nwg = nbx * gridDim.y;
  int bid = blockIdx.y * nbx + blockIdx.x;
  bid = (bid & 7) * (nwg >> 3) + (bid >> 3);   // XCD swizzle (nwg % 8 == 0)
  const int m0 = (bid % nbx) * 256;
  const int n0 = (bid / nbx) * 256;

  const int t = threadIdx.x;
  const int lane = t & 63;
  const int w = t >> 6;
  const int wm = w >> 2;
  const int wn = w & 3;
  const int l15 = lane & 15;
  const int kg = lane >> 4;

  const int srow = t >> 3;
  const int schunk = (t & 7) ^ (srow & 7);
  const bf16* Aaddr = A + (size_t)(m0 + srow) * K + schunk * 8;
  const bf16* Baddr = Bt + (size_t)(n0 + srow) * K + schunk * 8;

  const int NT = K >> 6;
  const int NITER = NT >> 1;

  const int arow = wm * 128 + l15;
  const int brow = wn * 64 + l15;
  const int c0 = (kg ^ (l15 & 7)) * 16;
  const int c1 = ((4 + kg) ^ (l15 & 7)) * 16;

  f32x4 acc[8][4];
#pragma unroll
  for (int i = 0; i < 8; i++)
#pragma unroll
    for (int j = 0; j < 4; j++) { f32x4 z = {0, 0, 0, 0}; acc[i][j] = z; }

#define STG_A(buf, q, kt) gload_lds16(Aaddr + (size_t)(q) * 64 * K + (kt) * 64, \
                                      (char*)&Al[buf][0] + (q) * 8192 + w * 1024)
#define STG_B(buf, q, kt) gload_lds16(Baddr + (size_t)(q) * 64 * K + (kt) * 64, \
                                      (char*)&Bl[buf][0] + (q) * 8192 + w * 1024)
#define RD_A(buf, aq) \
  _Pragma("unroll") for (int ii = 0; ii < 4; ii++) { \
    const char* p_ = (const char*)&Al[buf][0] + (size_t)(arow + (aq) * 64 + ii * 16) * 128; \
    af[ii][0] = *(const bf16x8*)(p_ + c0); \
    af[ii][1] = *(const bf16x8*)(p_ + c1); }
#define RD_B(buf) \
  _Pragma("unroll") for (int jj = 0; jj < 4; jj++) { \
    const char* p_ = (const char*)&Bl[buf][0] + (size_t)(brow + jj * 16) * 128; \
    bfr[jj][0] = *(const bf16x8*)(p_ + c0); \
    bfr[jj][1] = *(const bf16x8*)(p_ + c1); }
#define MM(iofs, j0) \
  _Pragma("unroll") for (int ii = 0; ii < 4; ii++) \
  _Pragma("unroll") for (int jj = (j0); jj < (j0) + 2; jj++) { \
    acc[(iofs) + ii][jj] = __builtin_amdgcn_mfma_f32_16x16x32_bf16(af[ii][0], bfr[jj][0], acc[(iofs) + ii][jj], 0, 0, 0); \
    acc[(iofs) + ii][jj] = __builtin_amdgcn_mfma_f32_16x16x32_bf16(af[ii][1], bfr[jj][1], acc[(iofs) + ii][jj], 0, 0, 0); }
#define BARX __builtin_amdgcn_s_barrier()
#define LGKMD asm volatile("s_waitcnt lgkmcnt(0)" ::: "memory")
#define PRI1 __builtin_amdgcn_s_setprio(1)
#define PRI0 __builtin_amdgcn_s_setprio(0)

#pragma unroll
  for (int q = 0; q < 4; q++) { STG_B(0, q, 0); }
#pragma unroll
  for (int q = 0; q < 4; q++) { STG_A(0, q, 0); }
#pragma unroll
  for (int q = 0; q < 4; q++) { STG_B(1, q, 1); }
#pragma unroll
  for (int q = 0; q < 4; q++) { STG_A(1, q, 1); }
  asm volatile("s_waitcnt vmcnt(8)" ::: "memory");
  BARX;

  bf16x8 af[4][2], bfr[4][2];

  for (int it = 0; it < NITER; it++) {
    const int kt0 = 2 * it;
    const bool st = (it + 1) < NITER;

    // P1: reads A[0]q02-rows + B[0]; MFMA i0-3 x j0-1 (compiler interleaves)
    RD_A(0, 0); RD_B(0);
    PRI1; MM(0, 0); PRI0; LGKMD; BARX;
    // P2: stage B[0]q0,q1 <- kt0+2 (B reads complete at P1 end); MFMA i0-3 x j2-3
    if (st) { STG_B(0, 0, kt0 + 2); STG_B(0, 1, kt0 + 2); }
    PRI1; MM(0, 2); PRI0; BARX;
    // P3: reads A[0]q13-rows; stage B[0]q2,q3; MFMA i4-7 x j0-1
    RD_A(0, 1);
    if (st) { STG_B(0, 2, kt0 + 2); STG_B(0, 3, kt0 + 2); }
    PRI1; MM(4, 0); PRI0; LGKMD; BARX;
    // P4: stage A[0]q0,q2 (reads complete at P1 end); MFMA i4-7 x j2-3; vmcnt(6)
    if (st) { STG_A(0, 0, kt0 + 2); STG_A(0, 2, kt0 + 2); }
    PRI1; MM(4, 2); PRI0;
    asm volatile("s_waitcnt vmcnt(6)" ::: "memory");
    BARX;

    // P5: reads buf1; stage A[0]q1,q3 (reads complete at P3 end)
    RD_A(1, 0); RD_B(1);
    if (st) { STG_A(0, 1, kt0 + 2); STG_A(0, 3, kt0 + 2); }
    PRI1; MM(0, 0); PRI0; LGKMD; BARX;
    // P6: stage B[1]q0,q1 <- kt0+3
    if (st) { STG_B(1, 0, kt0 + 3); STG_B(1, 1, kt0 + 3); }
    PRI1; MM(0, 2); PRI0; BARX;
    // P7: reads A[1]q13-rows; stage B[1]q2,q3
    RD_A(1, 1);
    if (st) { STG_B(1, 2, kt0 + 3); STG_B(1, 3, kt0 + 3); }
    PRI1; MM(4, 0); PRI0; LGKMD; BARX;
    // P8: stage A[1]q0-q3; vmcnt(8)
    if (st) { STG_A(1, 0, kt0 + 3); STG_A(1, 1, kt0 + 3);
              STG_A(1, 2, kt0 + 3); STG_A(1, 3, kt0 + 3); }
    PRI1; MM(4, 2); PRI0;
    asm volatile("s_waitcnt vmcnt(8)" ::: "memory");
    BARX;
  }

#undef STG_A
#undef STG_B
#undef RD_A
#undef RD_B
#undef MM
#undef BARX
#undef LGKMD
#undef PRI1
#undef PRI0

  float bs[4];
#pragma unroll
  for (int j = 0; j < 4; j++) bs[j] = bias[n0 + wn * 64 + j * 16 + l15];
#pragma unroll
  for (int i = 0; i < 8; i++)
#pragma unroll
    for (int j = 0; j < 4; j++)
#pragma unroll
      for (int rr = 0; rr < 4; rr++) {
        const int row = m0 + wm * 128 + i * 16 + kg * 4 + rr;
        const int col = n0 + wn * 64 + j * 16 + l15;
        C[(size_t)row * N + col] = (OutT)(acc[i][j][rr] + bs[j]);
      }
}

// ---------------- fused pool + rkv GEMV ----------------
__global__ __launch_bounds__(256) void pool_rkv_kernel(
    const bf16* __restrict__ xb, const bf16* __restrict__ rkv_wt,
    const float* __restrict__ rkv_b, bf16* __restrict__ rkvb)
{
  __shared__ float prow[1024];
  const int blk = blockIdx.x;
  const int b = blk >> 6, lt = blk & 63;
  const int t = threadIdx.x;

  const bf16* px = xb + ((size_t)b * S_ + lt * 64) * 1024 + t * 4;
  float s0 = 0.f, s1 = 0.f, s2 = 0.f, s3 = 0.f;
#pragma unroll
  for (int c = 0; c < 64; c++) {
    bf16x4 v = *(const bf16x4*)(px + (size_t)c * 1024);
    s0 += (float)v[0]; s1 += (float)v[1]; s2 += (float)v[2]; s3 += (float)v[3];
  }
  prow[t * 4 + 0] = s0 * 0.015625f;
  prow[t * 4 + 1] = s1 * 0.015625f;
  prow[t * 4 + 2] = s2 * 0.015625f;
  prow[t * 4 + 3] = s3 * 0.015625f;
  __syncthreads();

  const int n = blockIdx.y * 256 + t;
  const bf16* wcol = rkv_wt + (size_t)n * 1024;
  float s = rkv_b[n];
#pragma unroll 4
  for (int k = 0; k < 1024; k += 8) {
    bf16x8 wv = *(const bf16x8*)(wcol + k);
#pragma unroll
    for (int j = 0; j < 8; j++) s += prow[k + j] * (float)wv[j];
  }
  rkvb[(size_t)blk * 512 + n] = (bf16)s;
}

// ---------------- latent attention ----------------
__global__ __launch_bounds__(256) void latent_attn_kernel(
    const bf16* __restrict__ qkvrb, const bf16* __restrict__ rkvb,
    bf16* __restrict__ latout)
{
  __shared__ float rq_s[256];
  __shared__ float attn_s[4][64];
  const int blk = blockIdx.x;
  const int b = blk >> 12, s = blk & 4095;
  const int t = threadIdx.x;
  const int h = t >> 6, l = t & 63;
  const int cid = s >> 6;
  rq_s[t] = (float)qkvrb[((size_t)b * S_ + s) * QSTR + 3072 + t];
  __syncthreads();
  float val = -1e30f;
  if (l < cid) {
    const bf16* kr = rkvb + (size_t)(b * 64 + l) * 512 + h * 64;
    float sum = 0.f;
#pragma unroll
    for (int c = 0; c < 8; c++) {
      bf16x8 kv = *(const bf16x8*)(kr + c * 8);
#pragma unroll
      for (int j = 0; j < 8; j++) sum += rq_s[h * 64 + c * 8 + j] * (float)kv[j];
    }
    val = sum * 0.125f;
  }
  float mx = val;
#pragma unroll
  for (int off = 32; off; off >>= 1) mx = fmaxf(mx, __shfl_xor(mx, off));
  const float p = (l < cid) ? __expf(val - mx) : 0.f;
  float sm = p;
#pragma unroll
  for (int off = 32; off; off >>= 1) sm += __shfl_xor(sm, off);
  attn_s[h][l] = (sm > 0.f) ? p / sm : 0.f;
  __syncthreads();
  float o = 0.f;
  const bf16* vb = rkvb + (size_t)b * 64 * 512 + 256 + h * 64 + l;
  for (int lat = 0; lat < cid; lat++) o += attn_s[h][lat] * (float)vb[(size_t)lat * 512];
  latout[((size_t)b * S_ + s) * 256 + h * 64 + l] = (bf16)o;
}

// ---------------- local attn + gate, v4: balanced pairing + 4 blocks/CU ----------------
__global__ __launch_bounds__(256, 4) void local_attn_gate(
    const bf16* __restrict__ qkv, const bf16* __restrict__ remote,
    const float* __restrict__ glw, const float* __restrict__ grw,
    bf16* __restrict__ mixedb)
{
  __shared__ __align__(16) bf16 Kl[128 * 72];
  __shared__ __align__(16) bf16 Vt[64 * 136];
  __shared__ __align__(16) bf16 Pl[4][16 * 136];

  const int q0 = blockIdx.x * 128;
  const int h  = blockIdx.y;
  const int b  = blockIdx.z;
  const int t  = threadIdx.x;
  const int w  = t >> 6;
  const int l  = t & 63;
  const int g  = l >> 4;
  const int l15 = l & 15;

  const bf16* qbase = qkv + (size_t)b * S_ * QSTR + h * 64;
  const bf16* kbase = qbase + 1024;
  const bf16* vbase = qbase + 2048;

  bf16* PlW = &Pl[w][0];

  const int kq = (t & 31) * 4;
  const int dh = (t >> 5) * 8;

  // qg tiles owned by this wave: slot 0 -> j=w, slot 1 -> j=7-w
  bf16x8 qf[2][2];
#pragma unroll
  for (int sl = 0; sl < 2; sl++) {
    const int j = sl ? 7 - w : w;
#pragma unroll
    for (int db = 0; db < 2; db++)
      qf[sl][db] = *(const bf16x8*)(qbase + (size_t)(q0 + j * 16 + l15) * QSTR + db * 32 + g * 8);
  }

  float m_[2][4], l_[2][4];
  f32x4 accO[2][4];
#pragma unroll
  for (int sl = 0; sl < 2; sl++) {
#pragma unroll
    for (int r = 0; r < 4; r++) { m_[sl][r] = -1e30f; l_[sl][r] = 0.f; }
#pragma unroll
    for (int dt = 0; dt < 4; dt++) { f32x4 z = {0,0,0,0}; accO[sl][dt] = z; }
  }

  const int tstart = (q0 == 0) ? 1 : 0;

  for (int tile = tstart; tile < 2; tile++) {
    const int base = q0 - 128 + tile * 128;
    bf16x8 kreg[4], vreg[4];
#pragma unroll
    for (int i = 0; i < 4; i++) {
      const int c = i * 256 + t;
      const int kk = c >> 3, dc = c & 7;
      kreg[i] = *(const bf16x8*)(kbase + (size_t)(base + kk) * QSTR + dc * 8);
    }
#pragma unroll
    for (int i = 0; i < 4; i++)
      vreg[i] = *(const bf16x8*)(vbase + (size_t)(base + kq + i) * QSTR + dh);

    __syncthreads();
#pragma unroll
    for (int i = 0; i < 4; i++) {
      const int c = i * 256 + t;
      const int kk = c >> 3, dc = c & 7;
      *(bf16x8*)&Kl[kk * 72 + dc * 8] = kreg[i];
    }
#pragma unroll
    for (int j = 0; j < 8; j++) {
      bf16x4 wv = {vreg[0][j], vreg[1][j], vreg[2][j], vreg[3][j]};
      *(bf16x4*)&Vt[(dh + j) * 136 + kq] = wv;
    }
    __syncthreads();

#pragma unroll
    for (int sl = 0; sl < 2; sl++) {
      const int j = sl ? 7 - w : w;
      const int lo = (tile == 0) ? (j & ~1) : 0;
      const int hi = (tile == 0) ? 8 : ((j & ~1) + 2);

      f32x4 s[8];
#pragma unroll
      for (int kk = 0; kk < 8; kk++) {
        if (kk < lo || kk >= hi) continue;
        f32x4 z = {0,0,0,0};
        s[kk] = z;
        const bf16x8 kf0 = *(const bf16x8*)&Kl[(kk * 16 + l15) * 72 + g * 8];
        const bf16x8 kf1 = *(const bf16x8*)&Kl[(kk * 16 + l15) * 72 + 32 + g * 8];
        s[kk] = __builtin_amdgcn_mfma_f32_16x16x32_bf16(qf[sl][0], kf0, s[kk], 0, 0, 0);
        s[kk] = __builtin_amdgcn_mfma_f32_16x16x32_bf16(qf[sl][1], kf1, s[kk], 0, 0, 0);
      }
#pragma unroll
      for (int kk = 0; kk < 8; kk++) {
        if (kk < lo || kk >= hi) continue;
        const int kr = kk * 16 + l15;
#pragma unroll
        for (int r = 0; r < 4; r++) {
          const int qr = j * 16 + g * 4 + r;
          const bool ok = (tile == 0) ? (kr >= qr) : (kr < qr);
          s[kk][r] = ok ? s[kk][r] * 0.125f : -1e9f;
        }
      }
      float corr[4];
#pragma unroll
      for (int r = 0; r < 4; r++) {
        float v = -1e30f;
#pragma unroll
        for (int kk = 0; kk < 8; kk++) { if (kk < lo || kk >= hi) continue; v = fmaxf(v, s[kk][r]); }
        v = fmaxf(v, __shfl_xor(v, 1));
        v = fmaxf(v, __shfl_xor(v, 2));
        v = fmaxf(v, __shfl_xor(v, 4));
        v = fmaxf(v, __shfl_xor(v, 8));
        const float mn = fmaxf(m_[sl][r], v);
        corr[r] = __expf(m_[sl][r] - mn);
        m_[sl][r] = mn;
      }
      float rs[4] = {0.f, 0.f, 0.f, 0.f};
#pragma unroll
      for (int kk = 0; kk < 8; kk++) {
        if (kk < lo || kk >= hi) continue;
#pragma unroll
        for (int r = 0; r < 4; r++) {
          const float sv = s[kk][r];
          const float p = (sv > -5e8f) ? __expf(sv - m_[sl][r]) : 0.f;
          rs[r] += p;
          PlW[(g * 4 + r) * 136 + kk * 16 + l15] = (bf16)p;
        }
      }
#pragma unroll
      for (int r = 0; r < 4; r++) {
        float v = rs[r];
        v += __shfl_xor(v, 1); v += __shfl_xor(v, 2);
        v += __shfl_xor(v, 4); v += __shfl_xor(v, 8);
        l_[sl][r] = l_[sl][r] * corr[r] + v;
#pragma unroll
        for (int dt = 0; dt < 4; dt++) accO[sl][dt][r] *= corr[r];
      }
      asm volatile("s_waitcnt lgkmcnt(0)" ::: "memory");
      __builtin_amdgcn_sched_barrier(0);
      const int clo = (tile == 0) ? (j >> 1) : 0;
      const int chi = (tile == 0) ? 4 : ((j >> 1) + 1);
#pragma unroll
      for (int kc = 0; kc < 4; kc++) {
        if (kc < clo || kc >= chi) continue;
        const bf16x8 pa = *(const bf16x8*)&PlW[l15 * 136 + kc * 32 + g * 8];
#pragma unroll
        for (int dt = 0; dt < 4; dt++) {
          const bf16x8 vf = *(const bf16x8*)&Vt[(dt * 16 + l15) * 136 + kc * 32 + g * 8];
          accO[sl][dt] = __builtin_amdgcn_mfma_f32_16x16x32_bf16(pa, vf, accO[sl][dt], 0, 0, 0);
        }
      }
    }
  }

  // ---- fused gate + mix epilogue ----
  float glv[4], grv[4];
#pragma unroll
  for (int dt = 0; dt < 4; dt++) {
    glv[dt] = glw[dt * 16 + l15];
    grv[dt] = grw[dt * 16 + l15];
  }
  bf16* outp = mixedb + ((size_t)b * S_ + q0) * 1024 + h * 64;
  const bf16* rbase = remote + ((size_t)b * S_ + q0) * 1024 + h * 64;
#pragma unroll
  for (int sl = 0; sl < 2; sl++) {
    const int j = sl ? 7 - w : w;
#pragma unroll
    for (int r = 0; r < 4; r++) {
      const int row = j * 16 + g * 4 + r;
      const float inv = (l_[sl][r] > 0.f) ? 1.f / l_[sl][r] : 0.f;
      float lv[4], rv[4];
      float part = 0.f;
#pragma unroll
      for (int dt = 0; dt < 4; dt++) {
        lv[dt] = accO[sl][dt][r] * inv;
        rv[dt] = (float)rbase[(size_t)row * 1024 + dt * 16 + l15];
        part += lv[dt] * glv[dt] + rv[dt] * grv[dt];
      }
      part += __shfl_xor(part, 1);
      part += __shfl_xor(part, 2);
      part += __shfl_xor(part, 4);
      part += __shfl_xor(part, 8);
      const float gg = 1.f / (1.f + __expf(-part));
#pragma unroll
      for (int dt = 0; dt < 4; dt++)
        outp[(size_t)row * 1024 + dt * 16 + l15] = (bf16)(gg * lv[dt] + (1.f - gg) * rv[dt]);
    }
  }
}

// ---------------- launch ----------------
extern "C" void kernel_launch(void* const* d_in, const int* in_sizes, int n_in,
                              void* d_out, int out_size, void* d_ws, size_t ws_size,
                              hipStream_t stream)
{
  const float* x      = (const float*)d_in[0];
  const float* qkv_w  = (const float*)d_in[1];
  const float* qkv_b  = (const float*)d_in[2];
  const float* rq_w   = (const float*)d_in[3];
  const float* rq_b   = (const float*)d_in[4];
  const float* rkv_w  = (const float*)d_in[5];
  const float* rkv_b  = (const float*)d_in[6];
  const float* rout_w = (const float*)d_in[7];
  const float* rout_b = (const float*)d_in[8];
  const float* out_w  = (const float*)d_in[9];
  const float* out_b  = (const float*)d_in[10];
  const float* gl_w   = (const float*)d_in[11];
  const float* gr_w   = (const float*)d_in[12];

  char* w = (char*)d_ws;
  bf16* qkvr_wt = (bf16*)w; w += (size_t)QSTR * 1024 * 2;
  bf16* rkv_wt  = (bf16*)w; w += (size_t)512 * 1024 * 2;
  bf16* rout_wt = (bf16*)w; w += (size_t)1024 * 256 * 2;
  bf16* out_wt  = (bf16*)w; w += (size_t)1024 * 1024 * 2;
  float* qkvr_b = (float*)w; w += (size_t)QSTR * 4;
  bf16* xb      = (bf16*)w; w += (size_t)B_ * S_ * 1024 * 2;
  bf16* qkvrb   = (bf16*)w; w += (size_t)B_ * S_ * QSTR * 2;
  bf16* rkvb    = (bf16*)w; w += (size_t)B_ * 64 * 512 * 2;
  bf16* latout  = (bf16*)w; w += (size_t)B_ * S_ * 256 * 2;
  bf16* remote  = (bf16*)w; w += (size_t)B_ * S_ * 1024 * 2;
  bf16* mixedb  = (bf16*)w; w += (size_t)B_ * S_ * 1024 * 2;

  prep_kernel<<<dim3(7169), 256, 0, stream>>>(qkv_w, rq_w, rkv_w, rout_w, out_w, x,
                                              qkv_b, rq_b,
                                              qkvr_wt, rkv_wt, rout_wt, out_wt, xb, qkvr_b);

  gemm8_kernel<bf16><<<dim3(32, 13), 512, 0, stream>>>(xb, qkvr_wt, qkvr_b, qkvrb, B_ * S_, QSTR, 1024);
  pool_rkv_kernel<<<dim3(128, 2), 256, 0, stream>>>(xb, rkv_wt, rkv_b, rkvb);
  latent_attn_kernel<<<dim3(B_ * S_), 256, 0, stream>>>(qkvrb, rkvb, latout);
  gemm_bias_kernel<bf16><<<dim3(64, 8), 256, 0, stream>>>(latout, rout_wt, rout_b, remote, B_ * S_, 1024, 256);
  local_attn_gate<<<dim3(S_ / 128, 16, B_), 256, 0, stream>>>(qkvrb, remote, gl_w, gr_w, mixedb);
  gemm_bias_kernel<float><<<dim3(64, 8), 256, 0, stream>>>(mixedb, out_wt, out_b, (float*)d_out, B_ * S_, 1024, 1024);
}

// Round 14
// 216.155 us; speedup vs baseline: 1.6060x; 1.0016x over previous
//
#include <hip/hip_runtime.h>

typedef __bf16 bf16;
typedef bf16 bf16x4 __attribute__((ext_vector_type(4)));
typedef bf16 bf16x8 __attribute__((ext_vector_type(8)));
typedef float f32x4 __attribute__((ext_vector_type(4)));

#define B_ 2
#define S_ 4096
#define D_ 1024
#define QSTR 3328   // fused qkv+rq row stride

__device__ __forceinline__ void gload_lds16(const void* g, void* l) {
  __builtin_amdgcn_global_load_lds((const __attribute__((address_space(1))) void*)g,
                                   (__attribute__((address_space(3))) void*)l, 16, 0, 0);
}

// ---------------- fused prep: 5 weight transposes + convert + fused bias ----------------
__device__ __forceinline__ void transpose_block(
    const float* __restrict__ in, bf16* __restrict__ out, int K, int N,
    int bx, int by, float (*tile)[33], int tx, int ty)
{
  const int nb = bx * 32, kb = by * 32;
#pragma unroll
  for (int j = 0; j < 4; j++)
    tile[ty + j * 8][tx] = in[(size_t)(kb + ty + j * 8) * N + nb + tx];
  __syncthreads();
#pragma unroll
  for (int j = 0; j < 4; j++)
    out[(size_t)(nb + ty + j * 8) * K + kb + tx] = (bf16)tile[tx][ty + j * 8];
}

__global__ __launch_bounds__(256) void prep_kernel(
    const float* __restrict__ qkv_w, const float* __restrict__ rq_w,
    const float* __restrict__ rkv_w, const float* __restrict__ rout_w,
    const float* __restrict__ out_w, const float* __restrict__ x,
    const float* __restrict__ qkv_b, const float* __restrict__ rq_b,
    bf16* __restrict__ qkvr_wt, bf16* __restrict__ rkv_wt,
    bf16* __restrict__ rout_wt, bf16* __restrict__ out_wt,
    bf16* __restrict__ xb, float* __restrict__ qkvr_b)
{
  __shared__ float tile[32][33];
  const int t = threadIdx.x;
  const int tx = t & 31, ty = t >> 5;
  int bid = blockIdx.x;
  if (bid < 3072) {
    transpose_block(qkv_w, qkvr_wt, 1024, 3072, bid % 96, bid / 96, tile, tx, ty);
    return;
  }
  bid -= 3072;
  if (bid < 256) {
    transpose_block(rq_w, qkvr_wt + (size_t)3072 * 1024, 1024, 256, bid % 8, bid / 8, tile, tx, ty);
    return;
  }
  bid -= 256;
  if (bid < 512) {
    transpose_block(rkv_w, rkv_wt, 1024, 512, bid % 16, bid / 16, tile, tx, ty);
    return;
  }
  bid -= 512;
  if (bid < 256) {
    transpose_block(rout_w, rout_wt, 256, 1024, bid % 32, bid / 32, tile, tx, ty);
    return;
  }
  bid -= 256;
  if (bid < 1024) {
    transpose_block(out_w, out_wt, 1024, 1024, bid % 32, bid / 32, tile, tx, ty);
    return;
  }
  bid -= 1024;
  if (bid < 2048) {
    const int n4 = B_ * S_ * 1024 / 4;
    for (int i = bid * 256 + t; i < n4; i += 2048 * 256) {
      const float4 v = ((const float4*)x)[i];
      bf16x4 o = {(bf16)v.x, (bf16)v.y, (bf16)v.z, (bf16)v.w};
      *(bf16x4*)&xb[i * 4] = o;
    }
    return;
  }
  {
    for (int i = t; i < 3072; i += 256) qkvr_b[i] = qkv_b[i];
    if (t < 256) qkvr_b[3072 + t] = rq_b[t];
  }
}

// ---------------- 128-tile GEMM (balanced grids for N<=1024 shapes) ----------------
template <typename OutT>
__global__ __launch_bounds__(256) void gemm_bias_kernel(
    const bf16* __restrict__ A, const bf16* __restrict__ Bt,
    const float* __restrict__ bias, OutT* __restrict__ C,
    int M, int N, int K)
{
  __shared__ __align__(16) bf16 Al[128 * 32];
  __shared__ __align__(16) bf16 Bl[128 * 32];
  const int m0 = blockIdx.x * 128;
  const int n0 = blockIdx.y * 128;
  const int t = threadIdx.x;
  const int lane = t & 63;
  const int wave = t >> 6;
  const int wr = (wave >> 1) * 64;
  const int wc = (wave & 1) * 64;
  const int r16 = lane & 15;
  const int kg = lane >> 4;

  f32x4 acc[4][4];
#pragma unroll
  for (int i = 0; i < 4; i++)
#pragma unroll
    for (int j = 0; j < 4; j++) {
      f32x4 z = {0.f, 0.f, 0.f, 0.f};
      acc[i][j] = z;
    }

  for (int k0 = 0; k0 < K; k0 += 32) {
    __syncthreads();
#pragma unroll
    for (int i = 0; i < 2; i++) {
      const int o = i * 4096 + wave * 1024 + lane * 16;
      const int r = o >> 6;
      const int cb = o & 63;
      gload_lds16((const char*)(A + (size_t)(m0 + r) * K + k0) + cb,
                  (char*)Al + i * 4096 + wave * 1024);
      gload_lds16((const char*)(Bt + (size_t)(n0 + r) * K + k0) + cb,
                  (char*)Bl + i * 4096 + wave * 1024);
    }
    __syncthreads();
    bf16x8 a[4], b[4];
#pragma unroll
    for (int i = 0; i < 4; i++)
      a[i] = *(const bf16x8*)&Al[(wr + i * 16 + r16) * 32 + kg * 8];
#pragma unroll
    for (int i = 0; i < 4; i++)
      b[i] = *(const bf16x8*)&Bl[(wc + i * 16 + r16) * 32 + kg * 8];
#pragma unroll
    for (int i = 0; i < 4; i++)
#pragma unroll
      for (int j = 0; j < 4; j++)
        acc[i][j] = __builtin_amdgcn_mfma_f32_16x16x32_bf16(a[i], b[j], acc[i][j], 0, 0, 0);
  }

  float bs[4];
#pragma unroll
  for (int j = 0; j < 4; j++) bs[j] = bias[n0 + wc + j * 16 + r16];
#pragma unroll
  for (int i = 0; i < 4; i++)
#pragma unroll
    for (int j = 0; j < 4; j++)
#pragma unroll
      for (int r = 0; r < 4; r++) {
        const int row = m0 + wr + i * 16 + kg * 4 + r;
        const int col = n0 + wc + j * 16 + r16;
        C[(size_t)row * N + col] = (OutT)(acc[i][j][r] + bs[j]);
      }
}

// ---------------- 256x256 8-phase GEMM (frozen at r13 state) ----------------
template <typename OutT>
__global__ __launch_bounds__(512, 1) void gemm8_kernel(
    const bf16* __restrict__ A, const bf16* __restrict__ Bt,
    const float* __restrict__ bias, OutT* __restrict__ C,
    int M, int N, int K)
{
  __shared__ __align__(16) bf16 Al[2][256 * 64];
  __shared__ __align__(16) bf16 Bl[2][256 * 64];

  const int nbx = gridDim.x;
  const int nwg = nbx * gridDim.y;
  int bid = blockIdx.y * nbx + blockIdx.x;
  bid = (bid & 7) * (nwg >> 3) + (bid >> 3);   // XCD swizzle (nwg % 8 == 0)
  const int m0 = (bid % nbx) * 256;
  const int n0 = (bid / nbx) * 256;

  const int t = threadIdx.x;
  const int lane = t & 63;
  const int w = t >> 6;
  const int wm = w >> 2;
  const int wn = w & 3;
  const int l15 = lane & 15;
  const int kg = lane >> 4;

  const int srow = t >> 3;
  const int schunk = (t & 7) ^ (srow & 7);
  const bf16* Aaddr = A + (size_t)(m0 + srow) * K + schunk * 8;
  const bf16* Baddr = Bt + (size_t)(n0 + srow) * K + schunk * 8;

  const int NT = K >> 6;
  const int NITER = NT >> 1;

  const int arow = wm * 128 + l15;
  const int brow = wn * 64 + l15;
  const int c0 = (kg ^ (l15 & 7)) * 16;
  const int c1 = ((4 + kg) ^ (l15 & 7)) * 16;

  f32x4 acc[8][4];
#pragma unroll
  for (int i = 0; i < 8; i++)
#pragma unroll
    for (int j = 0; j < 4; j++) { f32x4 z = {0, 0, 0, 0}; acc[i][j] = z; }

#define STG_A(buf, q, kt) gload_lds16(Aaddr + (size_t)(q) * 64 * K + (kt) * 64, \
                                      (char*)&Al[buf][0] + (q) * 8192 + w * 1024)
#define STG_B(buf, q, kt) gload_lds16(Baddr + (size_t)(q) * 64 * K + (kt) * 64, \
                                      (char*)&Bl[buf][0] + (q) * 8192 + w * 1024)
#define RD_A(buf, aq) \
  _Pragma("unroll") for (int ii = 0; ii < 4; ii++) { \
    const char* p_ = (const char*)&Al[buf][0] + (size_t)(arow + (aq) * 64 + ii * 16) * 128; \
    af[ii][0] = *(const bf16x8*)(p_ + c0); \
    af[ii][1] = *(const bf16x8*)(p_ + c1); }
#define RD_B(buf) \
  _Pragma("unroll") for (int jj = 0; jj < 4; jj++) { \
    const char* p_ = (const char*)&Bl[buf][0] + (size_t)(brow + jj * 16) * 128; \
    bfr[jj][0] = *(const bf16x8*)(p_ + c0); \
    bfr[jj][1] = *(const bf16x8*)(p_ + c1); }
#define MM(iofs, j0) \
  _Pragma("unroll") for (int ii = 0; ii < 4; ii++) \
  _Pragma("unroll") for (int jj = (j0); jj < (j0) + 2; jj++) { \
    acc[(iofs) + ii][jj] = __builtin_amdgcn_mfma_f32_16x16x32_bf16(af[ii][0], bfr[jj][0], acc[(iofs) + ii][jj], 0, 0, 0); \
    acc[(iofs) + ii][jj] = __builtin_amdgcn_mfma_f32_16x16x32_bf16(af[ii][1], bfr[jj][1], acc[(iofs) + ii][jj], 0, 0, 0); }
#define BARX __builtin_amdgcn_s_barrier()
#define LGKMD asm volatile("s_waitcnt lgkmcnt(0)" ::: "memory")
#define PRI1 __builtin_amdgcn_s_setprio(1)
#define PRI0 __builtin_amdgcn_s_setprio(0)

#pragma unroll
  for (int q = 0; q < 4; q++) { STG_B(0, q, 0); }
#pragma unroll
  for (int q = 0; q < 4; q++) { STG_A(0, q, 0); }
#pragma unroll
  for (int q = 0; q < 4; q++) { STG_B(1, q, 1); }
#pragma unroll
  for (int q = 0; q < 4; q++) { STG_A(1, q, 1); }
  asm volatile("s_waitcnt vmcnt(8)" ::: "memory");
  BARX;

  bf16x8 af[4][2], bfr[4][2];

  for (int it = 0; it < NITER; it++) {
    const int kt0 = 2 * it;
    const bool st = (it + 1) < NITER;

    RD_A(0, 0); RD_B(0);
    PRI1; MM(0, 0); PRI0; LGKMD; BARX;
    if (st) { STG_B(0, 0, kt0 + 2); STG_B(0, 1, kt0 + 2); }
    PRI1; MM(0, 2); PRI0; BARX;
    RD_A(0, 1);
    if (st) { STG_B(0, 2, kt0 + 2); STG_B(0, 3, kt0 + 2); }
    PRI1; MM(4, 0); PRI0; LGKMD; BARX;
    if (st) { STG_A(0, 0, kt0 + 2); STG_A(0, 2, kt0 + 2); }
    PRI1; MM(4, 2); PRI0;
    asm volatile("s_waitcnt vmcnt(6)" ::: "memory");
    BARX;

    RD_A(1, 0); RD_B(1);
    if (st) { STG_A(0, 1, kt0 + 2); STG_A(0, 3, kt0 + 2); }
    PRI1; MM(0, 0); PRI0; LGKMD; BARX;
    if (st) { STG_B(1, 0, kt0 + 3); STG_B(1, 1, kt0 + 3); }
    PRI1; MM(0, 2); PRI0; BARX;
    RD_A(1, 1);
    if (st) { STG_B(1, 2, kt0 + 3); STG_B(1, 3, kt0 + 3); }
    PRI1; MM(4, 0); PRI0; LGKMD; BARX;
    if (st) { STG_A(1, 0, kt0 + 3); STG_A(1, 1, kt0 + 3);
              STG_A(1, 2, kt0 + 3); STG_A(1, 3, kt0 + 3); }
    PRI1; MM(4, 2); PRI0;
    asm volatile("s_waitcnt vmcnt(8)" ::: "memory");
    BARX;
  }

#undef STG_A
#undef STG_B
#undef RD_A
#undef RD_B
#undef MM
#undef BARX
#undef LGKMD
#undef PRI1
#undef PRI0

  float bs[4];
#pragma unroll
  for (int j = 0; j < 4; j++) bs[j] = bias[n0 + wn * 64 + j * 16 + l15];
#pragma unroll
  for (int i = 0; i < 8; i++)
#pragma unroll
    for (int j = 0; j < 4; j++)
#pragma unroll
      for (int rr = 0; rr < 4; rr++) {
        const int row = m0 + wm * 128 + i * 16 + kg * 4 + rr;
        const int col = n0 + wn * 64 + j * 16 + l15;
        C[(size_t)row * N + col] = (OutT)(acc[i][j][rr] + bs[j]);
      }
}

// ---------------- fused pool + rkv GEMV ----------------
__global__ __launch_bounds__(256) void pool_rkv_kernel(
    const bf16* __restrict__ xb, const bf16* __restrict__ rkv_wt,
    const float* __restrict__ rkv_b, bf16* __restrict__ rkvb)
{
  __shared__ float prow[1024];
  const int blk = blockIdx.x;
  const int b = blk >> 6, lt = blk & 63;
  const int t = threadIdx.x;

  const bf16* px = xb + ((size_t)b * S_ + lt * 64) * 1024 + t * 4;
  float s0 = 0.f, s1 = 0.f, s2 = 0.f, s3 = 0.f;
#pragma unroll
  for (int c = 0; c < 64; c++) {
    bf16x4 v = *(const bf16x4*)(px + (size_t)c * 1024);
    s0 += (float)v[0]; s1 += (float)v[1]; s2 += (float)v[2]; s3 += (float)v[3];
  }
  prow[t * 4 + 0] = s0 * 0.015625f;
  prow[t * 4 + 1] = s1 * 0.015625f;
  prow[t * 4 + 2] = s2 * 0.015625f;
  prow[t * 4 + 3] = s3 * 0.015625f;
  __syncthreads();

  const int n = blockIdx.y * 256 + t;
  const bf16* wcol = rkv_wt + (size_t)n * 1024;
  float s = rkv_b[n];
#pragma unroll 4
  for (int k = 0; k < 1024; k += 8) {
    bf16x8 wv = *(const bf16x8*)(wcol + k);
#pragma unroll
    for (int j = 0; j < 8; j++) s += prow[k + j] * (float)wv[j];
  }
  rkvb[(size_t)blk * 512 + n] = (bf16)s;
}

// ---------------- latent attention ----------------
__global__ __launch_bounds__(256) void latent_attn_kernel(
    const bf16* __restrict__ qkvrb, const bf16* __restrict__ rkvb,
    bf16* __restrict__ latout)
{
  __shared__ float rq_s[256];
  __shared__ float attn_s[4][64];
  const int blk = blockIdx.x;
  const int b = blk >> 12, s = blk & 4095;
  const int t = threadIdx.x;
  const int h = t >> 6, l = t & 63;
  const int cid = s >> 6;
  rq_s[t] = (float)qkvrb[((size_t)b * S_ + s) * QSTR + 3072 + t];
  __syncthreads();
  float val = -1e30f;
  if (l < cid) {
    const bf16* kr = rkvb + (size_t)(b * 64 + l) * 512 + h * 64;
    float sum = 0.f;
#pragma unroll
    for (int c = 0; c < 8; c++) {
      bf16x8 kv = *(const bf16x8*)(kr + c * 8);
#pragma unroll
      for (int j = 0; j < 8; j++) sum += rq_s[h * 64 + c * 8 + j] * (float)kv[j];
    }
    val = sum * 0.125f;
  }
  float mx = val;
#pragma unroll
  for (int off = 32; off; off >>= 1) mx = fmaxf(mx, __shfl_xor(mx, off));
  const float p = (l < cid) ? __expf(val - mx) : 0.f;
  float sm = p;
#pragma unroll
  for (int off = 32; off; off >>= 1) sm += __shfl_xor(sm, off);
  attn_s[h][l] = (sm > 0.f) ? p / sm : 0.f;
  __syncthreads();
  float o = 0.f;
  const bf16* vb = rkvb + (size_t)b * 64 * 512 + 256 + h * 64 + l;
  for (int lat = 0; lat < cid; lat++) o += attn_s[h][lat] * (float)vb[(size_t)lat * 512];
  latout[((size_t)b * S_ + s) * 256 + h * 64 + l] = (bf16)o;
}

// ---------------- local attn + gate, v5: coalesced V staging ----------------
// V-staging thread map changed to row=(t>>3)*4+i, d=(t&7)*8: 8 consecutive lanes
// read the SAME row's consecutive 16B chunks (dense 128B segments) instead of
// rows 26.6KB apart (64 partial cache lines per instr).
__global__ __launch_bounds__(256, 4) void local_attn_gate(
    const bf16* __restrict__ qkv, const bf16* __restrict__ remote,
    const float* __restrict__ glw, const float* __restrict__ grw,
    bf16* __restrict__ mixedb)
{
  __shared__ __align__(16) bf16 Kl[128 * 72];
  __shared__ __align__(16) bf16 Vt[64 * 136];
  __shared__ __align__(16) bf16 Pl[4][16 * 136];

  const int q0 = blockIdx.x * 128;
  const int h  = blockIdx.y;
  const int b  = blockIdx.z;
  const int t  = threadIdx.x;
  const int w  = t >> 6;
  const int l  = t & 63;
  const int g  = l >> 4;
  const int l15 = l & 15;

  const bf16* qbase = qkv + (size_t)b * S_ * QSTR + h * 64;
  const bf16* kbase = qbase + 1024;
  const bf16* vbase = qbase + 2048;

  bf16* PlW = &Pl[w][0];

  const int vrow = (t >> 3) * 4;   // 0,4,...,124
  const int vdh  = (t & 7) * 8;    // 0..56

  // qg tiles owned by this wave: slot 0 -> j=w, slot 1 -> j=7-w
  bf16x8 qf[2][2];
#pragma unroll
  for (int sl = 0; sl < 2; sl++) {
    const int j = sl ? 7 - w : w;
#pragma unroll
    for (int db = 0; db < 2; db++)
      qf[sl][db] = *(const bf16x8*)(qbase + (size_t)(q0 + j * 16 + l15) * QSTR + db * 32 + g * 8);
  }

  float m_[2][4], l_[2][4];
  f32x4 accO[2][4];
#pragma unroll
  for (int sl = 0; sl < 2; sl++) {
#pragma unroll
    for (int r = 0; r < 4; r++) { m_[sl][r] = -1e30f; l_[sl][r] = 0.f; }
#pragma unroll
    for (int dt = 0; dt < 4; dt++) { f32x4 z = {0,0,0,0}; accO[sl][dt] = z; }
  }

  const int tstart = (q0 == 0) ? 1 : 0;

  for (int tile = tstart; tile < 2; tile++) {
    const int base = q0 - 128 + tile * 128;
    bf16x8 kreg[4], vreg[4];
#pragma unroll
    for (int i = 0; i < 4; i++) {
      const int c = i * 256 + t;
      const int kk = c >> 3, dc = c & 7;
      kreg[i] = *(const bf16x8*)(kbase + (size_t)(base + kk) * QSTR + dc * 8);
    }
#pragma unroll
    for (int i = 0; i < 4; i++)
      vreg[i] = *(const bf16x8*)(vbase + (size_t)(base + vrow + i) * QSTR + vdh);

    __syncthreads();
#pragma unroll
    for (int i = 0; i < 4; i++) {
      const int c = i * 256 + t;
      const int kk = c >> 3, dc = c & 7;
      *(bf16x8*)&Kl[kk * 72 + dc * 8] = kreg[i];
    }
#pragma unroll
    for (int j = 0; j < 8; j++) {
      bf16x4 wv = {vreg[0][j], vreg[1][j], vreg[2][j], vreg[3][j]};
      *(bf16x4*)&Vt[(vdh + j) * 136 + vrow] = wv;
    }
    __syncthreads();

#pragma unroll
    for (int sl = 0; sl < 2; sl++) {
      const int j = sl ? 7 - w : w;
      const int lo = (tile == 0) ? (j & ~1) : 0;
      const int hi = (tile == 0) ? 8 : ((j & ~1) + 2);

      f32x4 s[8];
#pragma unroll
      for (int kk = 0; kk < 8; kk++) {
        if (kk < lo || kk >= hi) continue;
        f32x4 z = {0,0,0,0};
        s[kk] = z;
        const bf16x8 kf0 = *(const bf16x8*)&Kl[(kk * 16 + l15) * 72 + g * 8];
        const bf16x8 kf1 = *(const bf16x8*)&Kl[(kk * 16 + l15) * 72 + 32 + g * 8];
        s[kk] = __builtin_amdgcn_mfma_f32_16x16x32_bf16(qf[sl][0], kf0, s[kk], 0, 0, 0);
        s[kk] = __builtin_amdgcn_mfma_f32_16x16x32_bf16(qf[sl][1], kf1, s[kk], 0, 0, 0);
      }
#pragma unroll
      for (int kk = 0; kk < 8; kk++) {
        if (kk < lo || kk >= hi) continue;
        const int kr = kk * 16 + l15;
#pragma unroll
        for (int r = 0; r < 4; r++) {
          const int qr = j * 16 + g * 4 + r;
          const bool ok = (tile == 0) ? (kr >= qr) : (kr < qr);
          s[kk][r] = ok ? s[kk][r] * 0.125f : -1e9f;
        }
      }
      float corr[4];
#pragma unroll
      for (int r = 0; r < 4; r++) {
        float v = -1e30f;
#pragma unroll
        for (int kk = 0; kk < 8; kk++) { if (kk < lo || kk >= hi) continue; v = fmaxf(v, s[kk][r]); }
        v = fmaxf(v, __shfl_xor(v, 1));
        v = fmaxf(v, __shfl_xor(v, 2));
        v = fmaxf(v, __shfl_xor(v, 4));
        v = fmaxf(v, __shfl_xor(v, 8));
        const float mn = fmaxf(m_[sl][r], v);
        corr[r] = __expf(m_[sl][r] - mn);
        m_[sl][r] = mn;
      }
      float rs[4] = {0.f, 0.f, 0.f, 0.f};
#pragma unroll
      for (int kk = 0; kk < 8; kk++) {
        if (kk < lo || kk >= hi) continue;
#pragma unroll
        for (int r = 0; r < 4; r++) {
          const float sv = s[kk][r];
          const float p = (sv > -5e8f) ? __expf(sv - m_[sl][r]) : 0.f;
          rs[r] += p;
          PlW[(g * 4 + r) * 136 + kk * 16 + l15] = (bf16)p;
        }
      }
#pragma unroll
      for (int r = 0; r < 4; r++) {
        float v = rs[r];
        v += __shfl_xor(v, 1); v += __shfl_xor(v, 2);
        v += __shfl_xor(v, 4); v += __shfl_xor(v, 8);
        l_[sl][r] = l_[sl][r] * corr[r] + v;
#pragma unroll
        for (int dt = 0; dt < 4; dt++) accO[sl][dt][r] *= corr[r];
      }
      asm volatile("s_waitcnt lgkmcnt(0)" ::: "memory");
      __builtin_amdgcn_sched_barrier(0);
      const int clo = (tile == 0) ? (j >> 1) : 0;
      const int chi = (tile == 0) ? 4 : ((j >> 1) + 1);
#pragma unroll
      for (int kc = 0; kc < 4; kc++) {
        if (kc < clo || kc >= chi) continue;
        const bf16x8 pa = *(const bf16x8*)&PlW[l15 * 136 + kc * 32 + g * 8];
#pragma unroll
        for (int dt = 0; dt < 4; dt++) {
          const bf16x8 vf = *(const bf16x8*)&Vt[(dt * 16 + l15) * 136 + kc * 32 + g * 8];
          accO[sl][dt] = __builtin_amdgcn_mfma_f32_16x16x32_bf16(pa, vf, accO[sl][dt], 0, 0, 0);
        }
      }
    }
  }

  // ---- fused gate + mix epilogue ----
  float glv[4], grv[4];
#pragma unroll
  for (int dt = 0; dt < 4; dt++) {
    glv[dt] = glw[dt * 16 + l15];
    grv[dt] = grw[dt * 16 + l15];
  }
  bf16* outp = mixedb + ((size_t)b * S_ + q0) * 1024 + h * 64;
  const bf16* rbase = remote + ((size_t)b * S_ + q0) * 1024 + h * 64;
#pragma unroll
  for (int sl = 0; sl < 2; sl++) {
    const int j = sl ? 7 - w : w;
#pragma unroll
    for (int r = 0; r < 4; r++) {
      const int row = j * 16 + g * 4 + r;
      const float inv = (l_[sl][r] > 0.f) ? 1.f / l_[sl][r] : 0.f;
      float lv[4], rv[4];
      float part = 0.f;
#pragma unroll
      for (int dt = 0; dt < 4; dt++) {
        lv[dt] = accO[sl][dt][r] * inv;
        rv[dt] = (float)rbase[(size_t)row * 1024 + dt * 16 + l15];
        part += lv[dt] * glv[dt] + rv[dt] * grv[dt];
      }
      part += __shfl_xor(part, 1);
      part += __shfl_xor(part, 2);
      part += __shfl_xor(part, 4);
      part += __shfl_xor(part, 8);
      const float gg = 1.f / (1.f + __expf(-part));
#pragma unroll
      for (int dt = 0; dt < 4; dt++)
        outp[(size_t)row * 1024 + dt * 16 + l15] = (bf16)(gg * lv[dt] + (1.f - gg) * rv[dt]);
    }
  }
}

// ---------------- launch ----------------
extern "C" void kernel_launch(void* const* d_in, const int* in_sizes, int n_in,
                              void* d_out, int out_size, void* d_ws, size_t ws_size,
                              hipStream_t stream)
{
  const float* x      = (const float*)d_in[0];
  const float* qkv_w  = (const float*)d_in[1];
  const float* qkv_b  = (const float*)d_in[2];
  const float* rq_w   = (const float*)d_in[3];
  const float* rq_b   = (const float*)d_in[4];
  const float* rkv_w  = (const float*)d_in[5];
  const float* rkv_b  = (const float*)d_in[6];
  const float* rout_w = (const float*)d_in[7];
  const float* rout_b = (const float*)d_in[8];
  const float* out_w  = (const float*)d_in[9];
  const float* out_b  = (const float*)d_in[10];
  const float* gl_w   = (const float*)d_in[11];
  const float* gr_w   = (const float*)d_in[12];

  char* w = (char*)d_ws;
  bf16* qkvr_wt = (bf16*)w; w += (size_t)QSTR * 1024 * 2;
  bf16* rkv_wt  = (bf16*)w; w += (size_t)512 * 1024 * 2;
  bf16* rout_wt = (bf16*)w; w += (size_t)1024 * 256 * 2;
  bf16* out_wt  = (bf16*)w; w += (size_t)1024 * 1024 * 2;
  float* qkvr_b = (float*)w; w += (size_t)QSTR * 4;
  bf16* xb      = (bf16*)w; w += (size_t)B_ * S_ * 1024 * 2;
  bf16* qkvrb   = (bf16*)w; w += (size_t)B_ * S_ * QSTR * 2;
  bf16* rkvb    = (bf16*)w; w += (size_t)B_ * 64 * 512 * 2;
  bf16* latout  = (bf16*)w; w += (size_t)B_ * S_ * 256 * 2;
  bf16* remote  = (bf16*)w; w += (size_t)B_ * S_ * 1024 * 2;
  bf16* mixedb  = (bf16*)w; w += (size_t)B_ * S_ * 1024 * 2;

  prep_kernel<<<dim3(7169), 256, 0, stream>>>(qkv_w, rq_w, rkv_w, rout_w, out_w, x,
                                              qkv_b, rq_b,
                                              qkvr_wt, rkv_wt, rout_wt, out_wt, xb, qkvr_b);

  gemm8_kernel<bf16><<<dim3(32, 13), 512, 0, stream>>>(xb, qkvr_wt, qkvr_b, qkvrb, B_ * S_, QSTR, 1024);
  pool_rkv_kernel<<<dim3(128, 2), 256, 0, stream>>>(xb, rkv_wt, rkv_b, rkvb);
  latent_attn_kernel<<<dim3(B_ * S_), 256, 0, stream>>>(qkvrb, rkvb, latout);
  gemm_bias_kernel<bf16><<<dim3(64, 8), 256, 0, stream>>>(latout, rout_wt, rout_b, remote, B_ * S_, 1024, 256);
  local_attn_gate<<<dim3(S_ / 128, 16, B_), 256, 0, stream>>>(qkvrb, remote, gl_w, gr_w, mixedb);
  gemm_bias_kernel<float><<<dim3(64, 8), 256, 0, stream>>>(mixedb, out_wt, out_b, (float*)d_out, B_ * S_, 1024, 1024);
}

// Round 15
// 215.591 us; speedup vs baseline: 1.6102x; 1.0026x over previous
//
#include <hip/hip_runtime.h>

typedef __bf16 bf16;
typedef bf16 bf16x4 __attribute__((ext_vector_type(4)));
typedef bf16 bf16x8 __attribute__((ext_vector_type(8)));
typedef float f32x4 __attribute__((ext_vector_type(4)));

#define B_ 2
#define S_ 4096
#define D_ 1024
#define QSTR 3328   // fused qkv+rq row stride

__device__ __forceinline__ void gload_lds16(const void* g, void* l) {
  __builtin_amdgcn_global_load_lds((const __attribute__((address_space(1))) void*)g,
                                   (__attribute__((address_space(3))) void*)l, 16, 0, 0);
}

// ---------------- fused prep: 5 weight transposes + convert + fused bias ----------------
__device__ __forceinline__ void transpose_block(
    const float* __restrict__ in, bf16* __restrict__ out, int K, int N,
    int bx, int by, float (*tile)[33], int tx, int ty)
{
  const int nb = bx * 32, kb = by * 32;
#pragma unroll
  for (int j = 0; j < 4; j++)
    tile[ty + j * 8][tx] = in[(size_t)(kb + ty + j * 8) * N + nb + tx];
  __syncthreads();
#pragma unroll
  for (int j = 0; j < 4; j++)
    out[(size_t)(nb + ty + j * 8) * K + kb + tx] = (bf16)tile[tx][ty + j * 8];
}

__global__ __launch_bounds__(256) void prep_kernel(
    const float* __restrict__ qkv_w, const float* __restrict__ rq_w,
    const float* __restrict__ rkv_w, const float* __restrict__ rout_w,
    const float* __restrict__ out_w, const float* __restrict__ x,
    const float* __restrict__ qkv_b, const float* __restrict__ rq_b,
    bf16* __restrict__ qkvr_wt, bf16* __restrict__ rkv_wt,
    bf16* __restrict__ rout_wt, bf16* __restrict__ out_wt,
    bf16* __restrict__ xb, float* __restrict__ qkvr_b)
{
  __shared__ float tile[32][33];
  const int t = threadIdx.x;
  const int tx = t & 31, ty = t >> 5;
  int bid = blockIdx.x;
  if (bid < 3072) {
    transpose_block(qkv_w, qkvr_wt, 1024, 3072, bid % 96, bid / 96, tile, tx, ty);
    return;
  }
  bid -= 3072;
  if (bid < 256) {
    transpose_block(rq_w, qkvr_wt + (size_t)3072 * 1024, 1024, 256, bid % 8, bid / 8, tile, tx, ty);
    return;
  }
  bid -= 256;
  if (bid < 512) {
    transpose_block(rkv_w, rkv_wt, 1024, 512, bid % 16, bid / 16, tile, tx, ty);
    return;
  }
  bid -= 512;
  if (bid < 256) {
    transpose_block(rout_w, rout_wt, 256, 1024, bid % 32, bid / 32, tile, tx, ty);
    return;
  }
  bid -= 256;
  if (bid < 1024) {
    transpose_block(out_w, out_wt, 1024, 1024, bid % 32, bid / 32, tile, tx, ty);
    return;
  }
  bid -= 1024;
  if (bid < 2048) {
    const int n4 = B_ * S_ * 1024 / 4;
    for (int i = bid * 256 + t; i < n4; i += 2048 * 256) {
      const float4 v = ((const float4*)x)[i];
      bf16x4 o = {(bf16)v.x, (bf16)v.y, (bf16)v.z, (bf16)v.w};
      *(bf16x4*)&xb[i * 4] = o;
    }
    return;
  }
  {
    for (int i = t; i < 3072; i += 256) qkvr_b[i] = qkv_b[i];
    if (t < 256) qkvr_b[3072 + t] = rq_b[t];
  }
}

// ---------------- 128-tile GEMM (balanced grids for N<=1024 shapes) ----------------
template <typename OutT>
__global__ __launch_bounds__(256) void gemm_bias_kernel(
    const bf16* __restrict__ A, const bf16* __restrict__ Bt,
    const float* __restrict__ bias, OutT* __restrict__ C,
    int M, int N, int K)
{
  __shared__ __align__(16) bf16 Al[128 * 32];
  __shared__ __align__(16) bf16 Bl[128 * 32];
  const int m0 = blockIdx.x * 128;
  const int n0 = blockIdx.y * 128;
  const int t = threadIdx.x;
  const int lane = t & 63;
  const int wave = t >> 6;
  const int wr = (wave >> 1) * 64;
  const int wc = (wave & 1) * 64;
  const int r16 = lane & 15;
  const int kg = lane >> 4;

  f32x4 acc[4][4];
#pragma unroll
  for (int i = 0; i < 4; i++)
#pragma unroll
    for (int j = 0; j < 4; j++) {
      f32x4 z = {0.f, 0.f, 0.f, 0.f};
      acc[i][j] = z;
    }

  for (int k0 = 0; k0 < K; k0 += 32) {
    __syncthreads();
#pragma unroll
    for (int i = 0; i < 2; i++) {
      const int o = i * 4096 + wave * 1024 + lane * 16;
      const int r = o >> 6;
      const int cb = o & 63;
      gload_lds16((const char*)(A + (size_t)(m0 + r) * K + k0) + cb,
                  (char*)Al + i * 4096 + wave * 1024);
      gload_lds16((const char*)(Bt + (size_t)(n0 + r) * K + k0) + cb,
                  (char*)Bl + i * 4096 + wave * 1024);
    }
    __syncthreads();
    bf16x8 a[4], b[4];
#pragma unroll
    for (int i = 0; i < 4; i++)
      a[i] = *(const bf16x8*)&Al[(wr + i * 16 + r16) * 32 + kg * 8];
#pragma unroll
    for (int i = 0; i < 4; i++)
      b[i] = *(const bf16x8*)&Bl[(wc + i * 16 + r16) * 32 + kg * 8];
#pragma unroll
    for (int i = 0; i < 4; i++)
#pragma unroll
      for (int j = 0; j < 4; j++)
        acc[i][j] = __builtin_amdgcn_mfma_f32_16x16x32_bf16(a[i], b[j], acc[i][j], 0, 0, 0);
  }

  float bs[4];
#pragma unroll
  for (int j = 0; j < 4; j++) bs[j] = bias[n0 + wc + j * 16 + r16];
#pragma unroll
  for (int i = 0; i < 4; i++)
#pragma unroll
    for (int j = 0; j < 4; j++)
#pragma unroll
      for (int r = 0; r < 4; r++) {
        const int row = m0 + wr + i * 16 + kg * 4 + r;
        const int col = n0 + wc + j * 16 + r16;
        C[(size_t)row * N + col] = (OutT)(acc[i][j][r] + bs[j]);
      }
}

// ---------------- 256x256 8-phase GEMM (frozen at r13 state) ----------------
template <typename OutT>
__global__ __launch_bounds__(512, 1) void gemm8_kernel(
    const bf16* __restrict__ A, const bf16* __restrict__ Bt,
    const float* __restrict__ bias, OutT* __restrict__ C,
    int M, int N, int K)
{
  __shared__ __align__(16) bf16 Al[2][256 * 64];
  __shared__ __align__(16) bf16 Bl[2][256 * 64];

  const int nbx = gridDim.x;
  const int nwg = nbx * gridDim.y;
  int bid = blockIdx.y * nbx + blockIdx.x;
  bid = (bid & 7) * (nwg >> 3) + (bid >> 3);   // XCD swizzle (nwg % 8 == 0)
  const int m0 = (bid % nbx) * 256;
  const int n0 = (bid / nbx) * 256;

  const int t = threadIdx.x;
  const int lane = t & 63;
  const int w = t >> 6;
  const int wm = w >> 2;
  const int wn = w & 3;
  const int l15 = lane & 15;
  const int kg = lane >> 4;

  const int srow = t >> 3;
  const int schunk = (t & 7) ^ (srow & 7);
  const bf16* Aaddr = A + (size_t)(m0 + srow) * K + schunk * 8;
  const bf16* Baddr = Bt + (size_t)(n0 + srow) * K + schunk * 8;

  const int NT = K >> 6;
  const int NITER = NT >> 1;

  const int arow = wm * 128 + l15;
  const int brow = wn * 64 + l15;
  const int c0 = (kg ^ (l15 & 7)) * 16;
  const int c1 = ((4 + kg) ^ (l15 & 7)) * 16;

  f32x4 acc[8][4];
#pragma unroll
  for (int i = 0; i < 8; i++)
#pragma unroll
    for (int j = 0; j < 4; j++) { f32x4 z = {0, 0, 0, 0}; acc[i][j] = z; }

#define STG_A(buf, q, kt) gload_lds16(Aaddr + (size_t)(q) * 64 * K + (kt) * 64, \
                                      (char*)&Al[buf][0] + (q) * 8192 + w * 1024)
#define STG_B(buf, q, kt) gload_lds16(Baddr + (size_t)(q) * 64 * K + (kt) * 64, \
                                      (char*)&Bl[buf][0] + (q) * 8192 + w * 1024)
#define RD_A(buf, aq) \
  _Pragma("unroll") for (int ii = 0; ii < 4; ii++) { \
    const char* p_ = (const char*)&Al[buf][0] + (size_t)(arow + (aq) * 64 + ii * 16) * 128; \
    af[ii][0] = *(const bf16x8*)(p_ + c0); \
    af[ii][1] = *(const bf16x8*)(p_ + c1); }
#define RD_B(buf) \
  _Pragma("unroll") for (int jj = 0; jj < 4; jj++) { \
    const char* p_ = (const char*)&Bl[buf][0] + (size_t)(brow + jj * 16) * 128; \
    bfr[jj][0] = *(const bf16x8*)(p_ + c0); \
    bfr[jj][1] = *(const bf16x8*)(p_ + c1); }
#define MM(iofs, j0) \
  _Pragma("unroll") for (int ii = 0; ii < 4; ii++) \
  _Pragma("unroll") for (int jj = (j0); jj < (j0) + 2; jj++) { \
    acc[(iofs) + ii][jj] = __builtin_amdgcn_mfma_f32_16x16x32_bf16(af[ii][0], bfr[jj][0], acc[(iofs) + ii][jj], 0, 0, 0); \
    acc[(iofs) + ii][jj] = __builtin_amdgcn_mfma_f32_16x16x32_bf16(af[ii][1], bfr[jj][1], acc[(iofs) + ii][jj], 0, 0, 0); }
#define BARX __builtin_amdgcn_s_barrier()
#define LGKMD asm volatile("s_waitcnt lgkmcnt(0)" ::: "memory")
#define PRI1 __builtin_amdgcn_s_setprio(1)
#define PRI0 __builtin_amdgcn_s_setprio(0)

#pragma unroll
  for (int q = 0; q < 4; q++) { STG_B(0, q, 0); }
#pragma unroll
  for (int q = 0; q < 4; q++) { STG_A(0, q, 0); }
#pragma unroll
  for (int q = 0; q < 4; q++) { STG_B(1, q, 1); }
#pragma unroll
  for (int q = 0; q < 4; q++) { STG_A(1, q, 1); }
  asm volatile("s_waitcnt vmcnt(8)" ::: "memory");
  BARX;

  bf16x8 af[4][2], bfr[4][2];

  for (int it = 0; it < NITER; it++) {
    const int kt0 = 2 * it;
    const bool st = (it + 1) < NITER;

    RD_A(0, 0); RD_B(0);
    PRI1; MM(0, 0); PRI0; LGKMD; BARX;
    if (st) { STG_B(0, 0, kt0 + 2); STG_B(0, 1, kt0 + 2); }
    PRI1; MM(0, 2); PRI0; BARX;
    RD_A(0, 1);
    if (st) { STG_B(0, 2, kt0 + 2); STG_B(0, 3, kt0 + 2); }
    PRI1; MM(4, 0); PRI0; LGKMD; BARX;
    if (st) { STG_A(0, 0, kt0 + 2); STG_A(0, 2, kt0 + 2); }
    PRI1; MM(4, 2); PRI0;
    asm volatile("s_waitcnt vmcnt(6)" ::: "memory");
    BARX;

    RD_A(1, 0); RD_B(1);
    if (st) { STG_A(0, 1, kt0 + 2); STG_A(0, 3, kt0 + 2); }
    PRI1; MM(0, 0); PRI0; LGKMD; BARX;
    if (st) { STG_B(1, 0, kt0 + 3); STG_B(1, 1, kt0 + 3); }
    PRI1; MM(0, 2); PRI0; BARX;
    RD_A(1, 1);
    if (st) { STG_B(1, 2, kt0 + 3); STG_B(1, 3, kt0 + 3); }
    PRI1; MM(4, 0); PRI0; LGKMD; BARX;
    if (st) { STG_A(1, 0, kt0 + 3); STG_A(1, 1, kt0 + 3);
              STG_A(1, 2, kt0 + 3); STG_A(1, 3, kt0 + 3); }
    PRI1; MM(4, 2); PRI0;
    asm volatile("s_waitcnt vmcnt(8)" ::: "memory");
    BARX;
  }

#undef STG_A
#undef STG_B
#undef RD_A
#undef RD_B
#undef MM
#undef BARX
#undef LGKMD
#undef PRI1
#undef PRI0

  float bs[4];
#pragma unroll
  for (int j = 0; j < 4; j++) bs[j] = bias[n0 + wn * 64 + j * 16 + l15];
#pragma unroll
  for (int i = 0; i < 8; i++)
#pragma unroll
    for (int j = 0; j < 4; j++)
#pragma unroll
      for (int rr = 0; rr < 4; rr++) {
        const int row = m0 + wm * 128 + i * 16 + kg * 4 + rr;
        const int col = n0 + wn * 64 + j * 16 + l15;
        C[(size_t)row * N + col] = (OutT)(acc[i][j][rr] + bs[j]);
      }
}

// ---------------- fused pool + rkv GEMV ----------------
__global__ __launch_bounds__(256) void pool_rkv_kernel(
    const bf16* __restrict__ xb, const bf16* __restrict__ rkv_wt,
    const float* __restrict__ rkv_b, bf16* __restrict__ rkvb)
{
  __shared__ float prow[1024];
  const int blk = blockIdx.x;
  const int b = blk >> 6, lt = blk & 63;
  const int t = threadIdx.x;

  const bf16* px = xb + ((size_t)b * S_ + lt * 64) * 1024 + t * 4;
  float s0 = 0.f, s1 = 0.f, s2 = 0.f, s3 = 0.f;
#pragma unroll
  for (int c = 0; c < 64; c++) {
    bf16x4 v = *(const bf16x4*)(px + (size_t)c * 1024);
    s0 += (float)v[0]; s1 += (float)v[1]; s2 += (float)v[2]; s3 += (float)v[3];
  }
  prow[t * 4 + 0] = s0 * 0.015625f;
  prow[t * 4 + 1] = s1 * 0.015625f;
  prow[t * 4 + 2] = s2 * 0.015625f;
  prow[t * 4 + 3] = s3 * 0.015625f;
  __syncthreads();

  const int n = blockIdx.y * 256 + t;
  const bf16* wcol = rkv_wt + (size_t)n * 1024;
  float s = rkv_b[n];
#pragma unroll 4
  for (int k = 0; k < 1024; k += 8) {
    bf16x8 wv = *(const bf16x8*)(wcol + k);
#pragma unroll
    for (int j = 0; j < 8; j++) s += prow[k + j] * (float)wv[j];
  }
  rkvb[(size_t)blk * 512 + n] = (bf16)s;
}

// ---------------- latent attention ----------------
__global__ __launch_bounds__(256) void latent_attn_kernel(
    const bf16* __restrict__ qkvrb, const bf16* __restrict__ rkvb,
    bf16* __restrict__ latout)
{
  __shared__ float rq_s[256];
  __shared__ float attn_s[4][64];
  const int blk = blockIdx.x;
  const int b = blk >> 12, s = blk & 4095;
  const int t = threadIdx.x;
  const int h = t >> 6, l = t & 63;
  const int cid = s >> 6;
  rq_s[t] = (float)qkvrb[((size_t)b * S_ + s) * QSTR + 3072 + t];
  __syncthreads();
  float val = -1e30f;
  if (l < cid) {
    const bf16* kr = rkvb + (size_t)(b * 64 + l) * 512 + h * 64;
    float sum = 0.f;
#pragma unroll
    for (int c = 0; c < 8; c++) {
      bf16x8 kv = *(const bf16x8*)(kr + c * 8);
#pragma unroll
      for (int j = 0; j < 8; j++) sum += rq_s[h * 64 + c * 8 + j] * (float)kv[j];
    }
    val = sum * 0.125f;
  }
  float mx = val;
#pragma unroll
  for (int off = 32; off; off >>= 1) mx = fmaxf(mx, __shfl_xor(mx, off));
  const float p = (l < cid) ? __expf(val - mx) : 0.f;
  float sm = p;
#pragma unroll
  for (int off = 32; off; off >>= 1) sm += __shfl_xor(sm, off);
  attn_s[h][l] = (sm > 0.f) ? p / sm : 0.f;
  __syncthreads();
  float o = 0.f;
  const bf16* vb = rkvb + (size_t)b * 64 * 512 + 256 + h * 64 + l;
  for (int lat = 0; lat < cid; lat++) o += attn_s[h][lat] * (float)vb[(size_t)lat * 512];
  latout[((size_t)b * S_ + s) * 256 + h * 64 + l] = (bf16)o;
}

// ---------------- local attn + gate, v6: de-serialized slots ----------------
// Removed the manual lgkmcnt(0)+sched_barrier(0) before PV: the PlW->pa RAW is
// same-wave through compiler-visible loads/stores, so the compiler inserts its
// own partial waits; the full fence was blocking slot1 QK from overlapping
// slot0 softmax/PV. Added setprio around MFMA clusters (T5).
__global__ __launch_bounds__(256, 4) void local_attn_gate(
    const bf16* __restrict__ qkv, const bf16* __restrict__ remote,
    const float* __restrict__ glw, const float* __restrict__ grw,
    bf16* __restrict__ mixedb)
{
  __shared__ __align__(16) bf16 Kl[128 * 72];
  __shared__ __align__(16) bf16 Vt[64 * 136];
  __shared__ __align__(16) bf16 Pl[4][16 * 136];

  const int q0 = blockIdx.x * 128;
  const int h  = blockIdx.y;
  const int b  = blockIdx.z;
  const int t  = threadIdx.x;
  const int w  = t >> 6;
  const int l  = t & 63;
  const int g  = l >> 4;
  const int l15 = l & 15;

  const bf16* qbase = qkv + (size_t)b * S_ * QSTR + h * 64;
  const bf16* kbase = qbase + 1024;
  const bf16* vbase = qbase + 2048;

  bf16* PlW = &Pl[w][0];

  const int vrow = (t >> 3) * 4;
  const int vdh  = (t & 7) * 8;

  bf16x8 qf[2][2];
#pragma unroll
  for (int sl = 0; sl < 2; sl++) {
    const int j = sl ? 7 - w : w;
#pragma unroll
    for (int db = 0; db < 2; db++)
      qf[sl][db] = *(const bf16x8*)(qbase + (size_t)(q0 + j * 16 + l15) * QSTR + db * 32 + g * 8);
  }

  float m_[2][4], l_[2][4];
  f32x4 accO[2][4];
#pragma unroll
  for (int sl = 0; sl < 2; sl++) {
#pragma unroll
    for (int r = 0; r < 4; r++) { m_[sl][r] = -1e30f; l_[sl][r] = 0.f; }
#pragma unroll
    for (int dt = 0; dt < 4; dt++) { f32x4 z = {0,0,0,0}; accO[sl][dt] = z; }
  }

  const int tstart = (q0 == 0) ? 1 : 0;

  for (int tile = tstart; tile < 2; tile++) {
    const int base = q0 - 128 + tile * 128;
    bf16x8 kreg[4], vreg[4];
#pragma unroll
    for (int i = 0; i < 4; i++) {
      const int c = i * 256 + t;
      const int kk = c >> 3, dc = c & 7;
      kreg[i] = *(const bf16x8*)(kbase + (size_t)(base + kk) * QSTR + dc * 8);
    }
#pragma unroll
    for (int i = 0; i < 4; i++)
      vreg[i] = *(const bf16x8*)(vbase + (size_t)(base + vrow + i) * QSTR + vdh);

    __syncthreads();
#pragma unroll
    for (int i = 0; i < 4; i++) {
      const int c = i * 256 + t;
      const int kk = c >> 3, dc = c & 7;
      *(bf16x8*)&Kl[kk * 72 + dc * 8] = kreg[i];
    }
#pragma unroll
    for (int j = 0; j < 8; j++) {
      bf16x4 wv = {vreg[0][j], vreg[1][j], vreg[2][j], vreg[3][j]};
      *(bf16x4*)&Vt[(vdh + j) * 136 + vrow] = wv;
    }
    __syncthreads();

#pragma unroll
    for (int sl = 0; sl < 2; sl++) {
      const int j = sl ? 7 - w : w;
      const int lo = (tile == 0) ? (j & ~1) : 0;
      const int hi = (tile == 0) ? 8 : ((j & ~1) + 2);

      f32x4 s[8];
      __builtin_amdgcn_s_setprio(1);
#pragma unroll
      for (int kk = 0; kk < 8; kk++) {
        if (kk < lo || kk >= hi) continue;
        f32x4 z = {0,0,0,0};
        s[kk] = z;
        const bf16x8 kf0 = *(const bf16x8*)&Kl[(kk * 16 + l15) * 72 + g * 8];
        const bf16x8 kf1 = *(const bf16x8*)&Kl[(kk * 16 + l15) * 72 + 32 + g * 8];
        s[kk] = __builtin_amdgcn_mfma_f32_16x16x32_bf16(qf[sl][0], kf0, s[kk], 0, 0, 0);
        s[kk] = __builtin_amdgcn_mfma_f32_16x16x32_bf16(qf[sl][1], kf1, s[kk], 0, 0, 0);
      }
      __builtin_amdgcn_s_setprio(0);
#pragma unroll
      for (int kk = 0; kk < 8; kk++) {
        if (kk < lo || kk >= hi) continue;
        const int kr = kk * 16 + l15;
#pragma unroll
        for (int r = 0; r < 4; r++) {
          const int qr = j * 16 + g * 4 + r;
          const bool ok = (tile == 0) ? (kr >= qr) : (kr < qr);
          s[kk][r] = ok ? s[kk][r] * 0.125f : -1e9f;
        }
      }
      float corr[4];
#pragma unroll
      for (int r = 0; r < 4; r++) {
        float v = -1e30f;
#pragma unroll
        for (int kk = 0; kk < 8; kk++) { if (kk < lo || kk >= hi) continue; v = fmaxf(v, s[kk][r]); }
        v = fmaxf(v, __shfl_xor(v, 1));
        v = fmaxf(v, __shfl_xor(v, 2));
        v = fmaxf(v, __shfl_xor(v, 4));
        v = fmaxf(v, __shfl_xor(v, 8));
        const float mn = fmaxf(m_[sl][r], v);
        corr[r] = __expf(m_[sl][r] - mn);
        m_[sl][r] = mn;
      }
      float rs[4] = {0.f, 0.f, 0.f, 0.f};
#pragma unroll
      for (int kk = 0; kk < 8; kk++) {
        if (kk < lo || kk >= hi) continue;
#pragma unroll
        for (int r = 0; r < 4; r++) {
          const float sv = s[kk][r];
          const float p = (sv > -5e8f) ? __expf(sv - m_[sl][r]) : 0.f;
          rs[r] += p;
          PlW[(g * 4 + r) * 136 + kk * 16 + l15] = (bf16)p;
        }
      }
#pragma unroll
      for (int r = 0; r < 4; r++) {
        float v = rs[r];
        v += __shfl_xor(v, 1); v += __shfl_xor(v, 2);
        v += __shfl_xor(v, 4); v += __shfl_xor(v, 8);
        l_[sl][r] = l_[sl][r] * corr[r] + v;
#pragma unroll
        for (int dt = 0; dt < 4; dt++) accO[sl][dt][r] *= corr[r];
      }
      // no manual lgkm/sched fence: PlW->pa is a same-wave RAW the compiler orders
      const int clo = (tile == 0) ? (j >> 1) : 0;
      const int chi = (tile == 0) ? 4 : ((j >> 1) + 1);
      __builtin_amdgcn_s_setprio(1);
#pragma unroll
      for (int kc = 0; kc < 4; kc++) {
        if (kc < clo || kc >= chi) continue;
        const bf16x8 pa = *(const bf16x8*)&PlW[l15 * 136 + kc * 32 + g * 8];
#pragma unroll
        for (int dt = 0; dt < 4; dt++) {
          const bf16x8 vf = *(const bf16x8*)&Vt[(dt * 16 + l15) * 136 + kc * 32 + g * 8];
          accO[sl][dt] = __builtin_amdgcn_mfma_f32_16x16x32_bf16(pa, vf, accO[sl][dt], 0, 0, 0);
        }
      }
      __builtin_amdgcn_s_setprio(0);
    }
  }

  // ---- fused gate + mix epilogue ----
  float glv[4], grv[4];
#pragma unroll
  for (int dt = 0; dt < 4; dt++) {
    glv[dt] = glw[dt * 16 + l15];
    grv[dt] = grw[dt * 16 + l15];
  }
  bf16* outp = mixedb + ((size_t)b * S_ + q0) * 1024 + h * 64;
  const bf16* rbase = remote + ((size_t)b * S_ + q0) * 1024 + h * 64;
#pragma unroll
  for (int sl = 0; sl < 2; sl++) {
    const int j = sl ? 7 - w : w;
#pragma unroll
    for (int r = 0; r < 4; r++) {
      const int row = j * 16 + g * 4 + r;
      const float inv = (l_[sl][r] > 0.f) ? 1.f / l_[sl][r] : 0.f;
      float lv[4], rv[4];
      float part = 0.f;
#pragma unroll
      for (int dt = 0; dt < 4; dt++) {
        lv[dt] = accO[sl][dt][r] * inv;
        rv[dt] = (float)rbase[(size_t)row * 1024 + dt * 16 + l15];
        part += lv[dt] * glv[dt] + rv[dt] * grv[dt];
      }
      part += __shfl_xor(part, 1);
      part += __shfl_xor(part, 2);
      part += __shfl_xor(part, 4);
      part += __shfl_xor(part, 8);
      const float gg = 1.f / (1.f + __expf(-part));
#pragma unroll
      for (int dt = 0; dt < 4; dt++)
        outp[(size_t)row * 1024 + dt * 16 + l15] = (bf16)(gg * lv[dt] + (1.f - gg) * rv[dt]);
    }
  }
}

// ---------------- launch ----------------
extern "C" void kernel_launch(void* const* d_in, const int* in_sizes, int n_in,
                              void* d_out, int out_size, void* d_ws, size_t ws_size,
                              hipStream_t stream)
{
  const float* x      = (const float*)d_in[0];
  const float* qkv_w  = (const float*)d_in[1];
  const float* qkv_b  = (const float*)d_in[2];
  const float* rq_w   = (const float*)d_in[3];
  const float* rq_b   = (const float*)d_in[4];
  const float* rkv_w  = (const float*)d_in[5];
  const float* rkv_b  = (const float*)d_in[6];
  const float* rout_w = (const float*)d_in[7];
  const float* rout_b = (const float*)d_in[8];
  const float* out_w  = (const float*)d_in[9];
  const float* out_b  = (const float*)d_in[10];
  const float* gl_w   = (const float*)d_in[11];
  const float* gr_w   = (const float*)d_in[12];

  char* w = (char*)d_ws;
  bf16* qkvr_wt = (bf16*)w; w += (size_t)QSTR * 1024 * 2;
  bf16* rkv_wt  = (bf16*)w; w += (size_t)512 * 1024 * 2;
  bf16* rout_wt = (bf16*)w; w += (size_t)1024 * 256 * 2;
  bf16* out_wt  = (bf16*)w; w += (size_t)1024 * 1024 * 2;
  float* qkvr_b = (float*)w; w += (size_t)QSTR * 4;
  bf16* xb      = (bf16*)w; w += (size_t)B_ * S_ * 1024 * 2;
  bf16* qkvrb   = (bf16*)w; w += (size_t)B_ * S_ * QSTR * 2;
  bf16* rkvb    = (bf16*)w; w += (size_t)B_ * 64 * 512 * 2;
  bf16* latout  = (bf16*)w; w += (size_t)B_ * S_ * 256 * 2;
  bf16* remote  = (bf16*)w; w += (size_t)B_ * S_ * 1024 * 2;
  bf16* mixedb  = (bf16*)w; w += (size_t)B_ * S_ * 1024 * 2;

  prep_kernel<<<dim3(7169), 256, 0, stream>>>(qkv_w, rq_w, rkv_w, rout_w, out_w, x,
                                              qkv_b, rq_b,
                                              qkvr_wt, rkv_wt, rout_wt, out_wt, xb, qkvr_b);

  gemm8_kernel<bf16><<<dim3(32, 13), 512, 0, stream>>>(xb, qkvr_wt, qkvr_b, qkvrb, B_ * S_, QSTR, 1024);
  pool_rkv_kernel<<<dim3(128, 2), 256, 0, stream>>>(xb, rkv_wt, rkv_b, rkvb);
  latent_attn_kernel<<<dim3(B_ * S_), 256, 0, stream>>>(qkvrb, rkvb, latout);
  gemm_bias_kernel<bf16><<<dim3(64, 8), 256, 0, stream>>>(latout, rout_wt, rout_b, remote, B_ * S_, 1024, 256);
  local_attn_gate<<<dim3(S_ / 128, 16, B_), 256, 0, stream>>>(qkvrb, remote, gl_w, gr_w, mixedb);
  gemm_bias_kernel<float><<<dim3(64, 8), 256, 0, stream>>>(mixedb, out_wt, out_b, (float*)d_out, B_ * S_, 1024, 1024);
}